// Round 9
// baseline (436.387 us; speedup 1.0000x reference)
//
#include <hip/hip_runtime.h>
#include <math.h>

typedef __attribute__((ext_vector_type(8))) short short8;
typedef __attribute__((ext_vector_type(4))) float f32x4;
typedef unsigned short ushort_t;

#define KVIN 15360   // 15069 padded to 960*16 (split-K x16, K%32==0)

__device__ __forceinline__ ushort_t f2bf(float f) {
  unsigned u = __float_as_uint(f);
  return (ushort_t)((u + 0x7fffu + ((u >> 16) & 1u)) >> 16);  // RNE
}
__device__ __forceinline__ float bf2f(ushort_t h) {
  return __uint_as_float(((unsigned)h) << 16);
}

// ---------------- block reduction helpers (256-thread blocks) ----------------
__device__ __forceinline__ float blockReduceSum256(float v, float* red) {
  #pragma unroll
  for (int o = 32; o; o >>= 1) v += __shfl_xor(v, o);
  int wid = threadIdx.x >> 6, lane = threadIdx.x & 63;
  if (lane == 0) red[wid] = v;
  __syncthreads();
  v = red[0] + red[1] + red[2] + red[3];
  __syncthreads();
  return v;
}
__device__ __forceinline__ float blockReduceMax256(float v, float* red) {
  #pragma unroll
  for (int o = 32; o; o >>= 1) v = fmaxf(v, __shfl_xor(v, o));
  int wid = threadIdx.x >> 6, lane = threadIdx.x & 63;
  if (lane == 0) red[wid] = v;
  __syncthreads();
  v = fmaxf(fmaxf(red[0], red[1]), fmaxf(red[2], red[3]));
  __syncthreads();
  return v;
}

// ===== 1-pass bf16 MFMA GEMM, 64x128 tile, double-buffered LDS, 1 barrier/k-step =====
// C = A @ B^T (+bias). A: bf16. B: bf16 (BF16B) or fp32 (converted in staging).
// M % 64 == 0 via grid.y. N ragged (guarded). K%32==0; kChunk%32==0 (split-K via z).
// ZFAST: grid (z, mTile, nTile) - k-split fastest for XCD/L2 locality (vin).
// LDS: 16B unit (row,q) at unit-idx (row>>4)*64 + q*16 + (row&15)
//   -> frag read addr = base + 16*lane (conflict-free, proven R6-R8);
//      A: 256 units (1/thread), B: 512 units (2/thread). 2 buffers, 24 KB total.
// Waves 2x2: each computes 32(M) x 64(N): fa[2] x fb[4] -> 8 MFMA/k-step.
template <bool BF16B, bool BIAS, bool CAUSAL, bool POUT, bool ZFAST>
__global__ __launch_bounds__(256, 4) void glds2(
    const ushort_t* __restrict__ A, const void* __restrict__ Bv,
    const float* __restrict__ bias, float* __restrict__ C, ushort_t* __restrict__ Ch,
    int N, int K, int lda, int ldb, int ldc,
    int kChunk, long aZ, long bZ, long cZ)
{
  const int z  = ZFAST ? blockIdx.x : blockIdx.z;
  const int m0 = blockIdx.y * 64;
  const int n0 = (ZFAST ? blockIdx.z : blockIdx.x) * 128;
  if (CAUSAL && n0 > m0 + 63) return;   // tile fully above diagonal
  __shared__ ushort_t sA[2][2048], sB[2][4096];
  const int tid = threadIdx.x;
  const int kBeg = kChunk ? z * kChunk : 0;
  const int kEnd = kChunk ? kBeg + kChunk : K;
  A += (size_t)z * aZ;
  const ushort_t* Bh = (const ushort_t*)Bv;
  const float*    Bf = (const float*)Bv;
  if (BF16B) Bh += (size_t)z * bZ; else Bf += (size_t)z * bZ;
  C += (size_t)z * cZ;
  if (POUT) Ch += (size_t)z * cZ;

  // staging map: unit u -> row ((u>>6)<<4)|(u&15), k-quarter (u>>4)&3
  const int ar = ((tid >> 6) << 4) | (tid & 15);   // A row for unit tid (0..63)
  const int aq = (tid >> 4) & 3;
  const ushort_t* pA = A + (size_t)(m0 + ar) * lda + (aq << 3);
  // B units tid (rows 0..63) and tid+256 (rows 64..127), same q
  const int gn0 = n0 + ar, gn1 = n0 + ar + 64;
  const bool bok0 = gn0 < N, bok1 = gn1 < N;
  const ushort_t* pB0h = Bh + (size_t)gn0 * ldb + (aq << 3);
  const ushort_t* pB1h = Bh + (size_t)gn1 * ldb + (aq << 3);
  const float*    pB0f = Bf + (size_t)gn0 * ldb + (aq << 3);
  const float*    pB1f = Bf + (size_t)gn1 * ldb + (aq << 3);

  // waves 2x2: rows wrb*32, cols wcb*64
  const int lane = tid & 63;
  const int wrb = (tid >> 7) & 1;
  const int wcb = (tid >> 6) & 1;
  const int fr = lane & 15, fq = lane >> 4;

  f32x4 acc[2][4] = {};
  const short8 z8 = {0, 0, 0, 0, 0, 0, 0, 0};
  const float4 z4 = make_float4(0.f, 0.f, 0.f, 0.f);
  short8 rA, rB0, rB1;
  float4 f00, f01, f10, f11;

  // ---- prologue: load k0, stage into buf0, issue loads for k0+32 ----
  rA = *(const short8*)(pA + kBeg);
  if (BF16B) {
    rB0 = bok0 ? *(const short8*)(pB0h + kBeg) : z8;
    rB1 = bok1 ? *(const short8*)(pB1h + kBeg) : z8;
  } else {
    f00 = bok0 ? *(const float4*)(pB0f + kBeg) : z4;
    f01 = bok0 ? *(const float4*)(pB0f + kBeg + 4) : z4;
    f10 = bok1 ? *(const float4*)(pB1f + kBeg) : z4;
    f11 = bok1 ? *(const float4*)(pB1f + kBeg + 4) : z4;
  }
  {
    *(short8*)&sA[0][tid << 3] = rA;
    if (BF16B) {
      *(short8*)&sB[0][tid << 3] = rB0;
      *(short8*)&sB[0][(tid + 256) << 3] = rB1;
    } else {
      short8 s0, s1;
      #pragma unroll
      for (int j = 0; j < 4; ++j) {
        s0[j] = (short)f2bf(f00[j]); s0[j + 4] = (short)f2bf(f01[j]);
        s1[j] = (short)f2bf(f10[j]); s1[j + 4] = (short)f2bf(f11[j]);
      }
      *(short8*)&sB[0][tid << 3] = s0;
      *(short8*)&sB[0][(tid + 256) << 3] = s1;
    }
  }
  if (kBeg + 32 < kEnd) {
    const int k = kBeg + 32;
    rA = *(const short8*)(pA + k);
    if (BF16B) {
      rB0 = bok0 ? *(const short8*)(pB0h + k) : z8;
      rB1 = bok1 ? *(const short8*)(pB1h + k) : z8;
    } else {
      f00 = bok0 ? *(const float4*)(pB0f + k) : z4;
      f01 = bok0 ? *(const float4*)(pB0f + k + 4) : z4;
      f10 = bok1 ? *(const float4*)(pB1f + k) : z4;
      f11 = bok1 ? *(const float4*)(pB1f + k + 4) : z4;
    }
  }
  __syncthreads();

  int bufc = 0;
  for (int k0 = kBeg; k0 < kEnd; k0 += 32) {
    // ---- MFMA phase from buf[bufc] (reads: base + 16*lane, conflict-free) ----
    short8 fa[2], fb[4];
    #pragma unroll
    for (int f = 0; f < 2; ++f)
      fa[f] = *(const short8*)&sA[bufc][(((wrb << 1) + f) << 9) | (lane << 3)];
    #pragma unroll
    for (int g = 0; g < 4; ++g)
      fb[g] = *(const short8*)&sB[bufc][(((wcb << 2) + g) << 9) | (lane << 3)];
    #pragma unroll
    for (int f = 0; f < 2; ++f)
      #pragma unroll
      for (int g = 0; g < 4; ++g)
        acc[f][g] = __builtin_amdgcn_mfma_f32_16x16x32_bf16(fa[f], fb[g], acc[f][g], 0, 0, 0);

    // ---- stage k0+32 into the other buffer; issue loads for k0+64 ----
    if (k0 + 32 < kEnd) {
      const int nb = bufc ^ 1;
      *(short8*)&sA[nb][tid << 3] = rA;
      if (BF16B) {
        *(short8*)&sB[nb][tid << 3] = rB0;
        *(short8*)&sB[nb][(tid + 256) << 3] = rB1;
      } else {
        short8 s0, s1;
        #pragma unroll
        for (int j = 0; j < 4; ++j) {
          s0[j] = (short)f2bf(f00[j]); s0[j + 4] = (short)f2bf(f01[j]);
          s1[j] = (short)f2bf(f10[j]); s1[j + 4] = (short)f2bf(f11[j]);
        }
        *(short8*)&sB[nb][tid << 3] = s0;
        *(short8*)&sB[nb][(tid + 256) << 3] = s1;
      }
      if (k0 + 64 < kEnd) {
        const int k = k0 + 64;
        rA = *(const short8*)(pA + k);
        if (BF16B) {
          rB0 = bok0 ? *(const short8*)(pB0h + k) : z8;
          rB1 = bok1 ? *(const short8*)(pB1h + k) : z8;
        } else {
          f00 = bok0 ? *(const float4*)(pB0f + k) : z4;
          f01 = bok0 ? *(const float4*)(pB0f + k + 4) : z4;
          f10 = bok1 ? *(const float4*)(pB1f + k) : z4;
          f11 = bok1 ? *(const float4*)(pB1f + k + 4) : z4;
        }
      }
    }
    __syncthreads();
    bufc ^= 1;
  }

  // ---- epilogue: C/D layout col=lane&15, row=(lane>>4)*4+reg ----
  #pragma unroll
  for (int f = 0; f < 2; ++f) {
    const int gm = m0 + (wrb << 5) + f * 16 + fq * 4;
    #pragma unroll
    for (int g = 0; g < 4; ++g) {
      const int gn = n0 + (wcb << 6) + g * 16 + fr;
      if (gn < N) {
        #pragma unroll
        for (int i = 0; i < 4; ++i) {
          float v = acc[f][g][i];
          if (BIAS) v += bias[gn];
          const size_t o = (size_t)(gm + i) * ldc + gn;
          if (POUT) Ch[o] = f2bf(v);
          else      C[o] = v;
        }
      }
    }
  }
}

// ---------------- split-K combine: outh = bf16(sum_z part[z] + bias (+relu)) ----------------
template <bool RELU>
__global__ __launch_bounds__(256) void combine(
    const float* __restrict__ part, const float* __restrict__ bias,
    ushort_t* __restrict__ outh, int nz, long zstride, int total4, int N4)
{
  const int i = blockIdx.x * 256 + threadIdx.x;
  if (i >= total4) return;
  float4 s = ((const float4*)bias)[i % N4];
  for (int z = 0; z < nz; ++z) {
    float4 p = ((const float4*)(part + (size_t)z * zstride))[i];
    s.x += p.x; s.y += p.y; s.z += p.z; s.w += p.w;
  }
  if (RELU) {
    s.x = fmaxf(s.x, 0.f); s.y = fmaxf(s.y, 0.f);
    s.z = fmaxf(s.z, 0.f); s.w = fmaxf(s.w, 0.f);
  }
  ((ushort4*)outh)[i] = make_ushort4(f2bf(s.x), f2bf(s.y), f2bf(s.z), f2bf(s.w));
}

// ---------------- fused split-K combine + residual + LayerNorm ----------------
__global__ __launch_bounds__(256) void ln_parts(
    const float* __restrict__ part, int nz, const float* __restrict__ bias,
    float* __restrict__ x, ushort_t* __restrict__ xh,
    const float* __restrict__ g, const float* __restrict__ b)
{
  const int t = blockIdx.x, tid = threadIdx.x;
  float4 y = ((const float4*)(x + (size_t)t * 1024))[tid];
  float4 s = ((const float4*)bias)[tid];
  for (int z = 0; z < nz; ++z) {
    float4 p = ((const float4*)(part + (size_t)z * 524288 + (size_t)t * 1024))[tid];
    s.x += p.x; s.y += p.y; s.z += p.z; s.w += p.w;
  }
  y.x += s.x; y.y += s.y; y.z += s.z; y.w += s.w;
  __shared__ float red[4];
  float sum = blockReduceSum256(y.x + y.y + y.z + y.w, red);
  const float m = sum * (1.f / 1024.f);
  float dx = y.x - m, dy = y.y - m, dz = y.z - m, dw = y.w - m;
  float q = blockReduceSum256(dx * dx + dy * dy + dz * dz + dw * dw, red);
  const float rs = rsqrtf(q * (1.f / 1024.f) + 1e-5f);
  float4 gg = ((const float4*)g)[tid], bb = ((const float4*)b)[tid];
  float4 o;
  o.x = dx * rs * gg.x + bb.x;
  o.y = dy * rs * gg.y + bb.y;
  o.z = dz * rs * gg.z + bb.z;
  o.w = dw * rs * gg.w + bb.w;
  ((float4*)(x + (size_t)t * 1024))[tid] = o;
  ((ushort4*)xh)[t * 256 + tid] = make_ushort4(f2bf(o.x), f2bf(o.y), f2bf(o.z), f2bf(o.w));
}

// ---------------- vectorized fp32 -> bf16 conversions ----------------
__global__ __launch_bounds__(256) void cvt_flat(
    const float* __restrict__ src, ushort_t* __restrict__ dst, int total4)
{
  const int i = blockIdx.x * 256 + threadIdx.x;
  if (i >= total4) return;
  float4 v = ((const float4*)src)[i];
  ((ushort4*)dst)[i] = make_ushort4(f2bf(v.x), f2bf(v.y), f2bf(v.z), f2bf(v.w));
}

__global__ __launch_bounds__(256) void cvt_pad(
    const float* __restrict__ src, ushort_t* __restrict__ dst,
    int Csrc, int Cdst4, int total4)
{
  const int i = blockIdx.x * 256 + threadIdx.x;
  if (i >= total4) return;
  const int r = i / Cdst4;
  const int c = (i - r * Cdst4) << 2;
  const float* s = src + (size_t)r * Csrc + c;
  ushort4 o = make_ushort4(0, 0, 0, 0);
  if (c + 3 < Csrc) {
    o = make_ushort4(f2bf(s[0]), f2bf(s[1]), f2bf(s[2]), f2bf(s[3]));
  } else {
    if (c + 0 < Csrc) o.x = f2bf(s[0]);
    if (c + 1 < Csrc) o.y = f2bf(s[1]);
    if (c + 2 < Csrc) o.z = f2bf(s[2]);
    if (c + 3 < Csrc) o.w = f2bf(s[3]);
  }
  ((ushort4*)dst)[i] = o;
}

__global__ __launch_bounds__(256) void prep_vin_v(
    const float* __restrict__ vertice, const float* __restrict__ tmpl,
    ushort_t* __restrict__ dst, int total4)
{
  const int i = blockIdx.x * 256 + threadIdx.x;
  if (i >= total4) return;
  const int C4 = KVIN >> 2;
  const int t = i / C4;
  const int c = (i - t * C4) << 2;
  ushort4 o = make_ushort4(0, 0, 0, 0);
  if (t > 0) {
    const float* s = vertice + (size_t)(t - 1) * 15069 + c;
    if (c + 3 < 15069) {
      o = make_ushort4(f2bf(s[0] - tmpl[c]),     f2bf(s[1] - tmpl[c + 1]),
                       f2bf(s[2] - tmpl[c + 2]), f2bf(s[3] - tmpl[c + 3]));
    } else {
      if (c + 0 < 15069) o.x = f2bf(s[0] - tmpl[c]);
      if (c + 1 < 15069) o.y = f2bf(s[1] - tmpl[c + 1]);
      if (c + 2 < 15069) o.z = f2bf(s[2] - tmpl[c + 2]);
      if (c + 3 < 15069) o.w = f2bf(s[3] - tmpl[c + 3]);
    }
  }
  ((ushort4*)dst)[i] = o;
}

__global__ void prep_bias2(const float* __restrict__ one_hot, const float* __restrict__ W_obj,
                           const float* __restrict__ b_vm, float* __restrict__ bias2) {
  int d = blockIdx.x * 256 + threadIdx.x;
  if (d < 1024) {
    float s = 0.f;
    #pragma unroll
    for (int j = 0; j < 8; ++j) s += one_hot[j] * W_obj[d * 8 + j];
    bias2[d] = b_vm[d] + s;
  }
}

__global__ void prep_bias3(const float* __restrict__ b_vr, const float* __restrict__ tmpl,
                           float* __restrict__ bias3, int n) {
  int v = blockIdx.x * 256 + threadIdx.x;
  if (v < n) bias3[v] = b_vr[v] + tmpl[v];
}

// sum 16 vin split-K partials + bias2 + PE -> x (f32 + bf16)
__global__ __launch_bounds__(256) void reduce_pe(const float* __restrict__ part,
                                                 const float* __restrict__ bias2,
                                                 float* __restrict__ x,
                                                 ushort_t* __restrict__ xh) {
  const int t = blockIdx.x;
  const float PECOEF = -9.210340371976184f / 512.f;  // -ln(10000)/512
  const int p = t % 25;
  for (int d = threadIdx.x; d < 1024; d += 256) {
    float s = bias2[d];
    #pragma unroll
    for (int z = 0; z < 16; ++z) s += part[(size_t)z * 524288 + (size_t)t * 1024 + d];
    float arg = (float)p * expf((float)(d >> 1) * PECOEF);
    s += (d & 1) ? cosf(arg) : sinf(arg);
    const size_t idx = (size_t)t * 1024 + d;
    x[idx] = s;
    xh[idx] = f2bf(s);
  }
}

// V transpose from qkv split-K parts: vth[d][s] = bf16(sum_z part[z][s][2048+d] + bias)
__global__ __launch_bounds__(256) void vT_parts(const float* __restrict__ part,
                                                const float* __restrict__ bias,
                                                ushort_t* __restrict__ vth) {
  __shared__ float tile[32][33];
  const int s0 = blockIdx.x * 32, d0 = blockIdx.y * 32;
  const int tx = threadIdx.x & 31, ty = threadIdx.x >> 5;  // 32 x 8
  for (int r = ty; r < 32; r += 8) {
    float v = bias[2048 + d0 + tx];
    #pragma unroll
    for (int z = 0; z < 4; ++z)
      v += part[(size_t)z * 1572864 + (size_t)(s0 + r) * 3072 + 2048 + d0 + tx];
    tile[r][tx] = v;
  }
  __syncthreads();
  for (int r = ty; r < 32; r += 8)
    vth[(size_t)(d0 + r) * 512 + s0 + tx] = f2bf(tile[tx][r]);
}

// row softmax with ALIBI + causal; reads raw scores f32, writes attn bf16
__global__ __launch_bounds__(256) void softmax_alibi(const float* __restrict__ scores,
                                                     ushort_t* __restrict__ ah) {
  const int i = blockIdx.x, h = blockIdx.y;
  const size_t rb = ((size_t)h * 512 + i) * 512;
  const float* row = scores + rb;
  const int tid = threadIdx.x;
  const int len = i + 1;
  const float sl = exp2f(-2.f * (float)(h + 1));
  const int j0 = tid, j1 = tid + 256;
  float v0 = -INFINITY, v1 = -INFINITY;
  if (j0 < len) v0 = row[j0] * 0.0625f - sl * (float)((i - j0) / 25);
  if (j1 < len) v1 = row[j1] * 0.0625f - sl * (float)((i - j1) / 25);
  __shared__ float red[4];
  float m = blockReduceMax256(fmaxf(v0, v1), red);
  float e0 = (j0 < len) ? expf(v0 - m) : 0.f;
  float e1 = (j1 < len) ? expf(v1 - m) : 0.f;
  float s = blockReduceSum256(e0 + e1, red);
  float inv = 1.f / s;
  ah[rb + j0] = f2bf(e0 * inv);
  ah[rb + j1] = f2bf(e1 * inv);
}

// ---------------- host-side launch ----------------
extern "C" void kernel_launch(void* const* d_in, const int* in_sizes, int n_in,
                              void* d_out, int out_size, void* d_ws, size_t ws_size,
                              hipStream_t stream) {
  const float* audio   = (const float*)d_in[0];
  const float* vertice = (const float*)d_in[1];
  const float* tmpl    = (const float*)d_in[2];
  const float* one_hot = (const float*)d_in[3];
  const float* W_af    = (const float*)d_in[4];
  const float* b_af    = (const float*)d_in[5];
  const float* W_vm    = (const float*)d_in[6];
  const float* b_vm    = (const float*)d_in[7];
  const float* W_obj   = (const float*)d_in[8];
  const float* Wqkv_sa = (const float*)d_in[9];
  const float* bqkv_sa = (const float*)d_in[10];
  const float* Wo_sa   = (const float*)d_in[11];
  const float* bo_sa   = (const float*)d_in[12];
  const float* Wqkv_ca = (const float*)d_in[13];
  const float* bqkv_ca = (const float*)d_in[14];
  const float* Wo_ca   = (const float*)d_in[15];
  const float* bo_ca   = (const float*)d_in[16];
  const float* W1      = (const float*)d_in[17];
  const float* b1      = (const float*)d_in[18];
  const float* W2      = (const float*)d_in[19];
  const float* b2      = (const float*)d_in[20];
  const float* g1      = (const float*)d_in[21];
  const float* be1     = (const float*)d_in[22];
  const float* g2      = (const float*)d_in[23];
  const float* be2     = (const float*)d_in[24];
  const float* g3      = (const float*)d_in[25];
  const float* be3     = (const float*)d_in[26];
  const float* W_vr    = (const float*)d_in[27];
  const float* b_vr    = (const float*)d_in[28];
  float* out = (float*)d_out;

  // ---- workspace carve (floats), total ~100 MB ----
  float* base = (float*)d_ws;
  float* apF    = base;                  // 512*15360 us  = 3,932,160 fl
  float* wvmF   = apF + 3932160;         // 1024*15360 us = 7,864,320 fl (Wvm, then Wvr after vin)
  float* part   = wvmF + 7864320;        // 16*524288     = 8,388,608 fl
  float* x      = part + 8388608;        // 524,288
  float* xhF    = x + 524288;            // 262,144 (512*1024 us)
  float* audF   = xhF + 262144;          // 196,608 (512*768 us)
  float* hidF   = audF + 196608;         // 262,144
  float* qkvF   = hidF + 262144;         // 786,432 (512*3072 us)
  float* vtF    = qkvF + 786432;         // 262,144 (1024*512 us)
  float* scores = vtF + 262144;          // 1,048,576
  float* attF   = scores + 1048576;      // 524,288 (4*512*512 us)
  float* ctxF   = attF + 524288;         // 262,144
  float* cvF    = ctxF + 262144;         // 262,144
  float* h1F    = cvF + 262144;          // 524,288 (512*2048 us)
  float* bias2  = h1F + 524288;          // 1,024
  float* bias3  = bias2 + 1024;          // 15,072

  ushort_t* Aph  = (ushort_t*)apF;
  ushort_t* Wvmh = (ushort_t*)wvmF;
  ushort_t* Wvrh = (ushort_t*)wvmF;      // alias: Wvm dead after vin GEMM
  ushort_t* xh   = (ushort_t*)xhF;
  ushort_t* audh = (ushort_t*)audF;
  ushort_t* hidh = (ushort_t*)hidF;
  ushort_t* qkvh = (ushort_t*)qkvF;
  ushort_t* vth  = (ushort_t*)vtF;
  ushort_t* atth = (ushort_t*)attF;
  ushort_t* ctxh = (ushort_t*)ctxF;
  ushort_t* cvh  = (ushort_t*)cvF;
  ushort_t* h1h  = (ushort_t*)h1F;

  // ---- prep (all vectorized) ----
  prep_bias2<<<4, 256, 0, stream>>>(one_hot, W_obj, b_vm, bias2);
  prep_bias3<<<(15069 + 255) / 256, 256, 0, stream>>>(b_vr, tmpl, bias3, 15069);
  prep_vin_v<<<7680, 256, 0, stream>>>(vertice, tmpl, Aph, 512 * (KVIN / 4));
  cvt_pad<<<15360, 256, 0, stream>>>(W_vm, Wvmh, 15069, KVIN / 4, 1024 * (KVIN / 4));

  // ---- vin = Ap @ Wvm^T  (split-K x16, z-fastest, 1024 blocks) ----
  glds2<true, false, false, false, true><<<dim3(16, 8, 8), 256, 0, stream>>>(
      Aph, Wvmh, nullptr, part, nullptr,
      1024, KVIN, KVIN, KVIN, 1024, 960, 0, 0, 524288);
  reduce_pe<<<512, 256, 0, stream>>>(part, bias2, x, xh);

  // Wvr bf16 (reuse wvm region; Wvm dead after vin GEMM above)
  cvt_flat<<<15069, 256, 0, stream>>>(W_vr, Wvrh, 15069 * 256);

  // ---- hidden = audio @ W_af^T + b_af ----
  cvt_flat<<<384, 256, 0, stream>>>(audio, audh, 512 * 192);
  glds2<false, false, false, false, false><<<dim3(8, 8, 6), 256, 0, stream>>>(
      audh, W_af, nullptr, part, nullptr,
      1024, 768, 768, 768, 1024, 128, 0, 0, 524288);
  combine<false><<<512, 256, 0, stream>>>(part, b_af, hidh, 6, 524288, 131072, 256);

  // ---- self attention ----
  glds2<false, false, false, false, false><<<dim3(24, 8, 4), 256, 0, stream>>>(
      xh, Wqkv_sa, nullptr, part, nullptr,
      3072, 1024, 1024, 1024, 3072, 256, 0, 0, 1572864);
  combine<false><<<1536, 256, 0, stream>>>(part, bqkv_sa, qkvh, 4, 1572864, 393216, 768);
  vT_parts<<<dim3(16, 32), 256, 0, stream>>>(part, bqkv_sa, vth);
  // scores[h] = q_h @ k_h^T : z = head via kChunk=256 (causal tiles only)
  glds2<true, false, true, false, false><<<dim3(4, 8, 4), 256, 0, stream>>>(
      qkvh, qkvh + 1024, nullptr, scores, nullptr,
      512, 1024, 3072, 3072, 512, 256, 0, 0, 262144);
  softmax_alibi<<<dim3(512, 4), 256, 0, stream>>>(scores, atth);
  // ctx[h] = attn_h @ vT_h^T, bf16 out directly
  glds2<true, false, false, true, false><<<dim3(2, 8, 4), 256, 0, stream>>>(
      atth, vth, nullptr, nullptr, ctxh,
      256, 512, 512, 512, 1024, 0, 262144, 131072, 256);
  // out proj + LN
  glds2<false, false, false, false, false><<<dim3(8, 8, 8), 256, 0, stream>>>(
      ctxh, Wo_sa, nullptr, part, nullptr,
      1024, 1024, 1024, 1024, 1024, 128, 0, 0, 524288);
  ln_parts<<<512, 256, 0, stream>>>(part, 8, bo_sa, x, xh, g1, be1);

  // ---- cross attention: bool mask == identity -> V then O projection ----
  glds2<false, false, false, false, false><<<dim3(8, 8, 8), 256, 0, stream>>>(
      hidh, Wqkv_ca + (size_t)2048 * 1024, nullptr, part, nullptr,
      1024, 1024, 1024, 1024, 1024, 128, 0, 0, 524288);
  combine<false><<<512, 256, 0, stream>>>(part, bqkv_ca + 2048, cvh, 8, 524288, 131072, 256);
  glds2<false, false, false, false, false><<<dim3(8, 8, 8), 256, 0, stream>>>(
      cvh, Wo_ca, nullptr, part, nullptr,
      1024, 1024, 1024, 1024, 1024, 128, 0, 0, 524288);
  ln_parts<<<512, 256, 0, stream>>>(part, 8, bo_ca, x, xh, g2, be2);

  // ---- feed forward ----
  glds2<false, false, false, false, false><<<dim3(16, 8, 4), 256, 0, stream>>>(
      xh, W1, nullptr, part, nullptr,
      2048, 1024, 1024, 1024, 2048, 256, 0, 0, 1048576);
  combine<true><<<1024, 256, 0, stream>>>(part, b1, h1h, 4, 1048576, 262144, 512);
  glds2<false, false, false, false, false><<<dim3(8, 8, 8), 256, 0, stream>>>(
      h1h, W2, nullptr, part, nullptr,
      1024, 2048, 2048, 2048, 1024, 256, 0, 0, 524288);
  ln_parts<<<512, 256, 0, stream>>>(part, 8, b2, x, xh, g3, be3);

  // ---- final projection: out = x @ W_vr^T + (b_vr + tmpl)  (944 blocks) ----
  glds2<true, true, false, false, false><<<dim3(118, 8, 1), 256, 0, stream>>>(
      xh, Wvrh, bias3, out, nullptr,
      15069, 1024, 1024, 1024, 15069, 0, 0, 0, 0);
}

// Round 10
// 366.205 us; speedup vs baseline: 1.1916x; 1.1916x over previous
//
#include <hip/hip_runtime.h>
#include <math.h>

typedef __attribute__((ext_vector_type(8))) short short8;
typedef __attribute__((ext_vector_type(4))) float f32x4;
typedef unsigned short ushort_t;

#define KVIN 15360   // 15069 padded to 960*16 (split-K x16, K%32==0)

__device__ __forceinline__ ushort_t f2bf(float f) {
  unsigned u = __float_as_uint(f);
  return (ushort_t)((u + 0x7fffu + ((u >> 16) & 1u)) >> 16);  // RNE
}
__device__ __forceinline__ float bf2f(ushort_t h) {
  return __uint_as_float(((unsigned)h) << 16);
}

// ---------------- block reduction helpers (256-thread blocks) ----------------
__device__ __forceinline__ float blockReduceSum256(float v, float* red) {
  #pragma unroll
  for (int o = 32; o; o >>= 1) v += __shfl_xor(v, o);
  int wid = threadIdx.x >> 6, lane = threadIdx.x & 63;
  if (lane == 0) red[wid] = v;
  __syncthreads();
  v = red[0] + red[1] + red[2] + red[3];
  __syncthreads();
  return v;
}
__device__ __forceinline__ float blockReduceMax256(float v, float* red) {
  #pragma unroll
  for (int o = 32; o; o >>= 1) v = fmaxf(v, __shfl_xor(v, o));
  int wid = threadIdx.x >> 6, lane = threadIdx.x & 63;
  if (lane == 0) red[wid] = v;
  __syncthreads();
  v = fmaxf(fmaxf(red[0], red[1]), fmaxf(red[2], red[3]));
  __syncthreads();
  return v;
}

// ===== 1-pass bf16 MFMA GEMM, 128x128 tile, conflict-free LDS, depth-2 prefetch =====
// C = A @ B^T (+bias). A: bf16. B: bf16 (BF16B) or fp32 (converted in staging).
// M = 512 exact (grid.y=4). N ragged. K%32==0; kChunk%32==0, (kEnd-kBeg)/32 EVEN >= 2
// (all call sites satisfy: min 4 steps). Split-K via z; ZFAST: z = blockIdx.x.
// LDS: 16B unit (row,q) at unit-idx (row>>4)*64 + q*16 + (row&15)
//   -> frag read addr = base + 16*lane (conflict-free; SQ_LDS_BANK_CONFLICT==0 R6-R9).
// Depth-2 register prefetch: set X serves even k-steps, set Y odd; a load issued at
// step k is consumed at k+64 -> ~2 MFMA phases of slack cover HBM latency.
template <bool BF16B, bool BIAS, bool CAUSAL, bool POUT, bool ZFAST>
__global__ __launch_bounds__(256, 2) void glds3(
    const ushort_t* __restrict__ A, const void* __restrict__ Bv,
    const float* __restrict__ bias, float* __restrict__ C, ushort_t* __restrict__ Ch,
    int N, int K, int lda, int ldb, int ldc,
    int kChunk, long aZ, long bZ, long cZ)
{
  const int z  = ZFAST ? blockIdx.x : blockIdx.z;
  const int m0 = blockIdx.y * 128;
  const int n0 = (ZFAST ? blockIdx.z : blockIdx.x) * 128;
  if (CAUSAL && n0 > m0 + 127) return;   // tile fully above diagonal
  __shared__ ushort_t sA[4096], sB[4096];   // 512 units x 8 bf16 each
  const int tid = threadIdx.x;
  const int kBeg = kChunk ? z * kChunk : 0;
  const int kEnd = kChunk ? kBeg + kChunk : K;
  A += (size_t)z * aZ;
  const ushort_t* Bh = (const ushort_t*)Bv;
  const float*    Bf = (const float*)Bv;
  if (BF16B) Bh += (size_t)z * bZ; else Bf += (size_t)z * bZ;
  C += (size_t)z * cZ;
  if (POUT) Ch += (size_t)z * cZ;

  // staging map: thread t -> unit t (rows 0-63 region) and t+256 (rows 64-127)
  const int r0 = ((tid >> 6) << 4) | (tid & 15);   // unit t -> row
  const int q0 = (tid >> 4) & 3;                   // k-quarter within 32
  const int r1 = r0 + 64;
  const ushort_t* pA0 = A + (size_t)(m0 + r0) * lda + (q0 << 3);
  const ushort_t* pA1 = A + (size_t)(m0 + r1) * lda + (q0 << 3);
  const int gn0 = n0 + r0, gn1 = n0 + r1;
  const bool bok0 = gn0 < N, bok1 = gn1 < N;
  const ushort_t* pB0h = Bh + (size_t)gn0 * ldb + (q0 << 3);
  const ushort_t* pB1h = Bh + (size_t)gn1 * ldb + (q0 << 3);
  const float*    pB0f = Bf + (size_t)gn0 * ldb + (q0 << 3);
  const float*    pB1f = Bf + (size_t)gn1 * ldb + (q0 << 3);

  // waves 2x2, each 64x64
  const int lane = tid & 63;
  const int wrb = (tid >> 7) & 1;
  const int wcb = (tid >> 6) & 1;
  const int fr = lane & 15, fq = lane >> 4;

  f32x4 acc[4][4] = {};
  const short8 z8 = {0, 0, 0, 0, 0, 0, 0, 0};
  const float4 z4 = make_float4(0.f, 0.f, 0.f, 0.f);

  // two named register prefetch sets (static names -> no scratch, rule #20)
  short8 xa0, xa1, xb0, xb1; float4 xf0, xf1, xf2, xf3;
  short8 ya0, ya1, yb0, yb1; float4 yf0, yf1, yf2, yf3;

#define LOADX(KK) { xa0 = *(const short8*)(pA0 + (KK)); xa1 = *(const short8*)(pA1 + (KK)); \
  if (BF16B) { xb0 = bok0 ? *(const short8*)(pB0h + (KK)) : z8;                             \
               xb1 = bok1 ? *(const short8*)(pB1h + (KK)) : z8; }                           \
  else { xf0 = bok0 ? *(const float4*)(pB0f + (KK)) : z4;                                   \
         xf1 = bok0 ? *(const float4*)(pB0f + (KK) + 4) : z4;                               \
         xf2 = bok1 ? *(const float4*)(pB1f + (KK)) : z4;                                   \
         xf3 = bok1 ? *(const float4*)(pB1f + (KK) + 4) : z4; } }

#define LOADY(KK) { ya0 = *(const short8*)(pA0 + (KK)); ya1 = *(const short8*)(pA1 + (KK)); \
  if (BF16B) { yb0 = bok0 ? *(const short8*)(pB0h + (KK)) : z8;                             \
               yb1 = bok1 ? *(const short8*)(pB1h + (KK)) : z8; }                           \
  else { yf0 = bok0 ? *(const float4*)(pB0f + (KK)) : z4;                                   \
         yf1 = bok0 ? *(const float4*)(pB0f + (KK) + 4) : z4;                               \
         yf2 = bok1 ? *(const float4*)(pB1f + (KK)) : z4;                                   \
         yf3 = bok1 ? *(const float4*)(pB1f + (KK) + 4) : z4; } }

#define STAGEX() { *(short8*)&sA[tid << 3] = xa0; *(short8*)&sA[(tid + 256) << 3] = xa1;    \
  if (BF16B) { *(short8*)&sB[tid << 3] = xb0; *(short8*)&sB[(tid + 256) << 3] = xb1; }      \
  else { short8 s0_, s1_;                                                                   \
    _Pragma("unroll") for (int j = 0; j < 4; ++j) {                                         \
      s0_[j] = (short)f2bf(xf0[j]); s0_[j + 4] = (short)f2bf(xf1[j]);                       \
      s1_[j] = (short)f2bf(xf2[j]); s1_[j + 4] = (short)f2bf(xf3[j]); }                     \
    *(short8*)&sB[tid << 3] = s0_; *(short8*)&sB[(tid + 256) << 3] = s1_; } }

#define STAGEY() { *(short8*)&sA[tid << 3] = ya0; *(short8*)&sA[(tid + 256) << 3] = ya1;    \
  if (BF16B) { *(short8*)&sB[tid << 3] = yb0; *(short8*)&sB[(tid + 256) << 3] = yb1; }      \
  else { short8 s0_, s1_;                                                                   \
    _Pragma("unroll") for (int j = 0; j < 4; ++j) {                                         \
      s0_[j] = (short)f2bf(yf0[j]); s0_[j + 4] = (short)f2bf(yf1[j]);                       \
      s1_[j] = (short)f2bf(yf2[j]); s1_[j + 4] = (short)f2bf(yf3[j]); }                     \
    *(short8*)&sB[tid << 3] = s0_; *(short8*)&sB[(tid + 256) << 3] = s1_; } }

#define COMPUTE() { short8 fa[4], fb[4];                                                    \
  _Pragma("unroll") for (int f = 0; f < 4; ++f)                                             \
    fa[f] = *(const short8*)&sA[((((wrb << 2) + f) << 9) | (lane << 3))];                   \
  _Pragma("unroll") for (int g = 0; g < 4; ++g)                                             \
    fb[g] = *(const short8*)&sB[((((wcb << 2) + g) << 9) | (lane << 3))];                   \
  _Pragma("unroll") for (int f = 0; f < 4; ++f)                                             \
    _Pragma("unroll") for (int g = 0; g < 4; ++g)                                           \
      acc[f][g] = __builtin_amdgcn_mfma_f32_16x16x32_bf16(fa[f], fb[g], acc[f][g], 0, 0, 0); }

  // prologue: issue both sets
  LOADX(kBeg);
  LOADY(kBeg + 32);

  for (int k0 = kBeg; k0 < kEnd; k0 += 64) {
    // even step: stage X (loaded 2 steps ago), refill X for k0+64
    STAGEX();
    if (k0 + 64 < kEnd) LOADX(k0 + 64);
    __syncthreads();   // writes visible
    COMPUTE();
    __syncthreads();   // reads done before next stage
    // odd step: stage Y, refill Y for k0+96
    STAGEY();
    if (k0 + 96 < kEnd) LOADY(k0 + 96);
    __syncthreads();
    COMPUTE();
    __syncthreads();
  }

#undef LOADX
#undef LOADY
#undef STAGEX
#undef STAGEY
#undef COMPUTE

  // ---- epilogue: C/D layout col=lane&15, row=(lane>>4)*4+reg ----
  #pragma unroll
  for (int f = 0; f < 4; ++f) {
    const int gm = m0 + (wrb << 6) + f * 16 + fq * 4;
    #pragma unroll
    for (int g = 0; g < 4; ++g) {
      const int gn = n0 + (wcb << 6) + g * 16 + fr;
      if (gn < N) {
        #pragma unroll
        for (int i = 0; i < 4; ++i) {
          float v = acc[f][g][i];
          if (BIAS) v += bias[gn];
          const size_t o = (size_t)(gm + i) * ldc + gn;
          if (POUT) Ch[o] = f2bf(v);
          else      C[o] = v;
        }
      }
    }
  }
}

// ---------------- split-K combine: outh = bf16(sum_z part[z] + bias (+relu)) ----------------
template <bool RELU>
__global__ __launch_bounds__(256) void combine(
    const float* __restrict__ part, const float* __restrict__ bias,
    ushort_t* __restrict__ outh, int nz, long zstride, int total4, int N4)
{
  const int i = blockIdx.x * 256 + threadIdx.x;
  if (i >= total4) return;
  float4 s = ((const float4*)bias)[i % N4];
  for (int z = 0; z < nz; ++z) {
    float4 p = ((const float4*)(part + (size_t)z * zstride))[i];
    s.x += p.x; s.y += p.y; s.z += p.z; s.w += p.w;
  }
  if (RELU) {
    s.x = fmaxf(s.x, 0.f); s.y = fmaxf(s.y, 0.f);
    s.z = fmaxf(s.z, 0.f); s.w = fmaxf(s.w, 0.f);
  }
  ((ushort4*)outh)[i] = make_ushort4(f2bf(s.x), f2bf(s.y), f2bf(s.z), f2bf(s.w));
}

// ---------------- fused split-K combine + residual + LayerNorm ----------------
__global__ __launch_bounds__(256) void ln_parts(
    const float* __restrict__ part, int nz, const float* __restrict__ bias,
    float* __restrict__ x, ushort_t* __restrict__ xh,
    const float* __restrict__ g, const float* __restrict__ b)
{
  const int t = blockIdx.x, tid = threadIdx.x;
  float4 y = ((const float4*)(x + (size_t)t * 1024))[tid];
  float4 s = ((const float4*)bias)[tid];
  for (int z = 0; z < nz; ++z) {
    float4 p = ((const float4*)(part + (size_t)z * 524288 + (size_t)t * 1024))[tid];
    s.x += p.x; s.y += p.y; s.z += p.z; s.w += p.w;
  }
  y.x += s.x; y.y += s.y; y.z += s.z; y.w += s.w;
  __shared__ float red[4];
  float sum = blockReduceSum256(y.x + y.y + y.z + y.w, red);
  const float m = sum * (1.f / 1024.f);
  float dx = y.x - m, dy = y.y - m, dz = y.z - m, dw = y.w - m;
  float q = blockReduceSum256(dx * dx + dy * dy + dz * dz + dw * dw, red);
  const float rs = rsqrtf(q * (1.f / 1024.f) + 1e-5f);
  float4 gg = ((const float4*)g)[tid], bb = ((const float4*)b)[tid];
  float4 o;
  o.x = dx * rs * gg.x + bb.x;
  o.y = dy * rs * gg.y + bb.y;
  o.z = dz * rs * gg.z + bb.z;
  o.w = dw * rs * gg.w + bb.w;
  ((float4*)(x + (size_t)t * 1024))[tid] = o;
  ((ushort4*)xh)[t * 256 + tid] = make_ushort4(f2bf(o.x), f2bf(o.y), f2bf(o.z), f2bf(o.w));
}

// ---------------- vectorized fp32 -> bf16 conversions ----------------
__global__ __launch_bounds__(256) void cvt_flat(
    const float* __restrict__ src, ushort_t* __restrict__ dst, int total4)
{
  const int i = blockIdx.x * 256 + threadIdx.x;
  if (i >= total4) return;
  float4 v = ((const float4*)src)[i];
  ((ushort4*)dst)[i] = make_ushort4(f2bf(v.x), f2bf(v.y), f2bf(v.z), f2bf(v.w));
}

__global__ __launch_bounds__(256) void cvt_pad(
    const float* __restrict__ src, ushort_t* __restrict__ dst,
    int Csrc, int Cdst4, int total4)
{
  const int i = blockIdx.x * 256 + threadIdx.x;
  if (i >= total4) return;
  const int r = i / Cdst4;
  const int c = (i - r * Cdst4) << 2;
  const float* s = src + (size_t)r * Csrc + c;
  ushort4 o = make_ushort4(0, 0, 0, 0);
  if (c + 3 < Csrc) {
    o = make_ushort4(f2bf(s[0]), f2bf(s[1]), f2bf(s[2]), f2bf(s[3]));
  } else {
    if (c + 0 < Csrc) o.x = f2bf(s[0]);
    if (c + 1 < Csrc) o.y = f2bf(s[1]);
    if (c + 2 < Csrc) o.z = f2bf(s[2]);
    if (c + 3 < Csrc) o.w = f2bf(s[3]);
  }
  ((ushort4*)dst)[i] = o;
}

__global__ __launch_bounds__(256) void prep_vin_v(
    const float* __restrict__ vertice, const float* __restrict__ tmpl,
    ushort_t* __restrict__ dst, int total4)
{
  const int i = blockIdx.x * 256 + threadIdx.x;
  if (i >= total4) return;
  const int C4 = KVIN >> 2;
  const int t = i / C4;
  const int c = (i - t * C4) << 2;
  ushort4 o = make_ushort4(0, 0, 0, 0);
  if (t > 0) {
    const float* s = vertice + (size_t)(t - 1) * 15069 + c;
    if (c + 3 < 15069) {
      o = make_ushort4(f2bf(s[0] - tmpl[c]),     f2bf(s[1] - tmpl[c + 1]),
                       f2bf(s[2] - tmpl[c + 2]), f2bf(s[3] - tmpl[c + 3]));
    } else {
      if (c + 0 < 15069) o.x = f2bf(s[0] - tmpl[c]);
      if (c + 1 < 15069) o.y = f2bf(s[1] - tmpl[c + 1]);
      if (c + 2 < 15069) o.z = f2bf(s[2] - tmpl[c + 2]);
      if (c + 3 < 15069) o.w = f2bf(s[3] - tmpl[c + 3]);
    }
  }
  ((ushort4*)dst)[i] = o;
}

__global__ void prep_bias2(const float* __restrict__ one_hot, const float* __restrict__ W_obj,
                           const float* __restrict__ b_vm, float* __restrict__ bias2) {
  int d = blockIdx.x * 256 + threadIdx.x;
  if (d < 1024) {
    float s = 0.f;
    #pragma unroll
    for (int j = 0; j < 8; ++j) s += one_hot[j] * W_obj[d * 8 + j];
    bias2[d] = b_vm[d] + s;
  }
}

__global__ void prep_bias3(const float* __restrict__ b_vr, const float* __restrict__ tmpl,
                           float* __restrict__ bias3, int n) {
  int v = blockIdx.x * 256 + threadIdx.x;
  if (v < n) bias3[v] = b_vr[v] + tmpl[v];
}

// sum 16 vin split-K partials + bias2 + PE -> x (f32 + bf16)
__global__ __launch_bounds__(256) void reduce_pe(const float* __restrict__ part,
                                                 const float* __restrict__ bias2,
                                                 float* __restrict__ x,
                                                 ushort_t* __restrict__ xh) {
  const int t = blockIdx.x;
  const float PECOEF = -9.210340371976184f / 512.f;  // -ln(10000)/512
  const int p = t % 25;
  for (int d = threadIdx.x; d < 1024; d += 256) {
    float s = bias2[d];
    #pragma unroll
    for (int z = 0; z < 16; ++z) s += part[(size_t)z * 524288 + (size_t)t * 1024 + d];
    float arg = (float)p * expf((float)(d >> 1) * PECOEF);
    s += (d & 1) ? cosf(arg) : sinf(arg);
    const size_t idx = (size_t)t * 1024 + d;
    x[idx] = s;
    xh[idx] = f2bf(s);
  }
}

// V transpose from qkv split-K parts: vth[d][s] = bf16(sum_z part[z][s][2048+d] + bias)
__global__ __launch_bounds__(256) void vT_parts(const float* __restrict__ part,
                                                const float* __restrict__ bias,
                                                ushort_t* __restrict__ vth) {
  __shared__ float tile[32][33];
  const int s0 = blockIdx.x * 32, d0 = blockIdx.y * 32;
  const int tx = threadIdx.x & 31, ty = threadIdx.x >> 5;  // 32 x 8
  for (int r = ty; r < 32; r += 8) {
    float v = bias[2048 + d0 + tx];
    #pragma unroll
    for (int z = 0; z < 4; ++z)
      v += part[(size_t)z * 1572864 + (size_t)(s0 + r) * 3072 + 2048 + d0 + tx];
    tile[r][tx] = v;
  }
  __syncthreads();
  for (int r = ty; r < 32; r += 8)
    vth[(size_t)(d0 + r) * 512 + s0 + tx] = f2bf(tile[tx][r]);
}

// row softmax with ALIBI + causal; reads raw scores f32, writes attn bf16
__global__ __launch_bounds__(256) void softmax_alibi(const float* __restrict__ scores,
                                                     ushort_t* __restrict__ ah) {
  const int i = blockIdx.x, h = blockIdx.y;
  const size_t rb = ((size_t)h * 512 + i) * 512;
  const float* row = scores + rb;
  const int tid = threadIdx.x;
  const int len = i + 1;
  const float sl = exp2f(-2.f * (float)(h + 1));
  const int j0 = tid, j1 = tid + 256;
  float v0 = -INFINITY, v1 = -INFINITY;
  if (j0 < len) v0 = row[j0] * 0.0625f - sl * (float)((i - j0) / 25);
  if (j1 < len) v1 = row[j1] * 0.0625f - sl * (float)((i - j1) / 25);
  __shared__ float red[4];
  float m = blockReduceMax256(fmaxf(v0, v1), red);
  float e0 = (j0 < len) ? expf(v0 - m) : 0.f;
  float e1 = (j1 < len) ? expf(v1 - m) : 0.f;
  float s = blockReduceSum256(e0 + e1, red);
  float inv = 1.f / s;
  ah[rb + j0] = f2bf(e0 * inv);
  ah[rb + j1] = f2bf(e1 * inv);
}

// ---------------- host-side launch ----------------
extern "C" void kernel_launch(void* const* d_in, const int* in_sizes, int n_in,
                              void* d_out, int out_size, void* d_ws, size_t ws_size,
                              hipStream_t stream) {
  const float* audio   = (const float*)d_in[0];
  const float* vertice = (const float*)d_in[1];
  const float* tmpl    = (const float*)d_in[2];
  const float* one_hot = (const float*)d_in[3];
  const float* W_af    = (const float*)d_in[4];
  const float* b_af    = (const float*)d_in[5];
  const float* W_vm    = (const float*)d_in[6];
  const float* b_vm    = (const float*)d_in[7];
  const float* W_obj   = (const float*)d_in[8];
  const float* Wqkv_sa = (const float*)d_in[9];
  const float* bqkv_sa = (const float*)d_in[10];
  const float* Wo_sa   = (const float*)d_in[11];
  const float* bo_sa   = (const float*)d_in[12];
  const float* Wqkv_ca = (const float*)d_in[13];
  const float* bqkv_ca = (const float*)d_in[14];
  const float* Wo_ca   = (const float*)d_in[15];
  const float* bo_ca   = (const float*)d_in[16];
  const float* W1      = (const float*)d_in[17];
  const float* b1      = (const float*)d_in[18];
  const float* W2      = (const float*)d_in[19];
  const float* b2      = (const float*)d_in[20];
  const float* g1      = (const float*)d_in[21];
  const float* be1     = (const float*)d_in[22];
  const float* g2      = (const float*)d_in[23];
  const float* be2     = (const float*)d_in[24];
  const float* g3      = (const float*)d_in[25];
  const float* be3     = (const float*)d_in[26];
  const float* W_vr    = (const float*)d_in[27];
  const float* b_vr    = (const float*)d_in[28];
  float* out = (float*)d_out;

  // ---- workspace carve (floats), total ~100 MB ----
  float* base = (float*)d_ws;
  float* apF    = base;                  // 512*15360 us  = 3,932,160 fl
  float* wvmF   = apF + 3932160;         // 1024*15360 us = 7,864,320 fl (Wvm, then Wvr after vin)
  float* part   = wvmF + 7864320;        // 16*524288     = 8,388,608 fl
  float* x      = part + 8388608;        // 524,288
  float* xhF    = x + 524288;            // 262,144 (512*1024 us)
  float* audF   = xhF + 262144;          // 196,608 (512*768 us)
  float* hidF   = audF + 196608;         // 262,144
  float* qkvF   = hidF + 262144;         // 786,432 (512*3072 us)
  float* vtF    = qkvF + 786432;         // 262,144 (1024*512 us)
  float* scores = vtF + 262144;          // 1,048,576
  float* attF   = scores + 1048576;      // 524,288 (4*512*512 us)
  float* ctxF   = attF + 524288;         // 262,144
  float* cvF    = ctxF + 262144;         // 262,144
  float* h1F    = cvF + 262144;          // 524,288 (512*2048 us)
  float* bias2  = h1F + 524288;          // 1,024
  float* bias3  = bias2 + 1024;          // 15,072

  ushort_t* Aph  = (ushort_t*)apF;
  ushort_t* Wvmh = (ushort_t*)wvmF;
  ushort_t* Wvrh = (ushort_t*)wvmF;      // alias: Wvm dead after vin GEMM
  ushort_t* xh   = (ushort_t*)xhF;
  ushort_t* audh = (ushort_t*)audF;
  ushort_t* hidh = (ushort_t*)hidF;
  ushort_t* qkvh = (ushort_t*)qkvF;
  ushort_t* vth  = (ushort_t*)vtF;
  ushort_t* atth = (ushort_t*)attF;
  ushort_t* ctxh = (ushort_t*)ctxF;
  ushort_t* cvh  = (ushort_t*)cvF;
  ushort_t* h1h  = (ushort_t*)h1F;

  // ---- prep (all vectorized) ----
  prep_bias2<<<4, 256, 0, stream>>>(one_hot, W_obj, b_vm, bias2);
  prep_bias3<<<(15069 + 255) / 256, 256, 0, stream>>>(b_vr, tmpl, bias3, 15069);
  prep_vin_v<<<7680, 256, 0, stream>>>(vertice, tmpl, Aph, 512 * (KVIN / 4));
  cvt_pad<<<15360, 256, 0, stream>>>(W_vm, Wvmh, 15069, KVIN / 4, 1024 * (KVIN / 4));

  // ---- vin = Ap @ Wvm^T  (split-K x16, z-fastest for XCD/L2 locality) ----
  glds3<true, false, false, false, true><<<dim3(16, 4, 8), 256, 0, stream>>>(
      Aph, Wvmh, nullptr, part, nullptr,
      1024, KVIN, KVIN, KVIN, 1024, 960, 0, 0, 524288);
  reduce_pe<<<512, 256, 0, stream>>>(part, bias2, x, xh);

  // Wvr bf16 (reuse wvm region; Wvm dead after vin GEMM above)
  cvt_flat<<<15069, 256, 0, stream>>>(W_vr, Wvrh, 15069 * 256);

  // ---- hidden = audio @ W_af^T + b_af ----
  cvt_flat<<<384, 256, 0, stream>>>(audio, audh, 512 * 192);
  glds3<false, false, false, false, false><<<dim3(8, 4, 6), 256, 0, stream>>>(
      audh, W_af, nullptr, part, nullptr,
      1024, 768, 768, 768, 1024, 128, 0, 0, 524288);
  combine<false><<<512, 256, 0, stream>>>(part, b_af, hidh, 6, 524288, 131072, 256);

  // ---- self attention ----
  glds3<false, false, false, false, false><<<dim3(24, 4, 4), 256, 0, stream>>>(
      xh, Wqkv_sa, nullptr, part, nullptr,
      3072, 1024, 1024, 1024, 3072, 256, 0, 0, 1572864);
  combine<false><<<1536, 256, 0, stream>>>(part, bqkv_sa, qkvh, 4, 1572864, 393216, 768);
  vT_parts<<<dim3(16, 32), 256, 0, stream>>>(part, bqkv_sa, vth);
  // scores[h] = q_h @ k_h^T : z = head via kChunk=256 (causal tiles only)
  glds3<true, false, true, false, false><<<dim3(4, 4, 4), 256, 0, stream>>>(
      qkvh, qkvh + 1024, nullptr, scores, nullptr,
      512, 1024, 3072, 3072, 512, 256, 0, 0, 262144);
  softmax_alibi<<<dim3(512, 4), 256, 0, stream>>>(scores, atth);
  // ctx[h] = attn_h @ vT_h^T, bf16 out directly
  glds3<true, false, false, true, false><<<dim3(2, 4, 4), 256, 0, stream>>>(
      atth, vth, nullptr, nullptr, ctxh,
      256, 512, 512, 512, 1024, 0, 262144, 131072, 256);
  // out proj + LN
  glds3<false, false, false, false, false><<<dim3(8, 4, 8), 256, 0, stream>>>(
      ctxh, Wo_sa, nullptr, part, nullptr,
      1024, 1024, 1024, 1024, 1024, 128, 0, 0, 524288);
  ln_parts<<<512, 256, 0, stream>>>(part, 8, bo_sa, x, xh, g1, be1);

  // ---- cross attention: bool mask == identity -> V then O projection ----
  glds3<false, false, false, false, false><<<dim3(8, 4, 8), 256, 0, stream>>>(
      hidh, Wqkv_ca + (size_t)2048 * 1024, nullptr, part, nullptr,
      1024, 1024, 1024, 1024, 1024, 128, 0, 0, 524288);
  combine<false><<<512, 256, 0, stream>>>(part, bqkv_ca + 2048, cvh, 8, 524288, 131072, 256);
  glds3<false, false, false, false, false><<<dim3(8, 4, 8), 256, 0, stream>>>(
      cvh, Wo_ca, nullptr, part, nullptr,
      1024, 1024, 1024, 1024, 1024, 128, 0, 0, 524288);
  ln_parts<<<512, 256, 0, stream>>>(part, 8, bo_ca, x, xh, g2, be2);

  // ---- feed forward ----
  glds3<false, false, false, false, false><<<dim3(16, 4, 4), 256, 0, stream>>>(
      xh, W1, nullptr, part, nullptr,
      2048, 1024, 1024, 1024, 2048, 256, 0, 0, 1048576);
  combine<true><<<1024, 256, 0, stream>>>(part, b1, h1h, 4, 1048576, 262144, 512);
  glds3<false, false, false, false, false><<<dim3(8, 4, 8), 256, 0, stream>>>(
      h1h, W2, nullptr, part, nullptr,
      1024, 2048, 2048, 2048, 1024, 256, 0, 0, 524288);
  ln_parts<<<512, 256, 0, stream>>>(part, 8, b2, x, xh, g3, be3);

  // ---- final projection: out = x @ W_vr^T + (b_vr + tmpl)  (pre-split bf16 B) ----
  glds3<true, true, false, false, false><<<dim3(118, 4, 1), 256, 0, stream>>>(
      xh, Wvrh, bias3, out, nullptr,
      15069, 1024, 1024, 1024, 15069, 0, 0, 0, 0);
}

// Round 11
// 357.694 us; speedup vs baseline: 1.2200x; 1.0238x over previous
//
#include <hip/hip_runtime.h>
#include <math.h>

typedef __attribute__((ext_vector_type(8))) short short8;
typedef __attribute__((ext_vector_type(4))) float f32x4;
typedef unsigned short ushort_t;

#define KVIN 15360   // 15069 padded to 960*16 (split-K x16, K%32==0)

__device__ __forceinline__ ushort_t f2bf(float f) {
  unsigned u = __float_as_uint(f);
  return (ushort_t)((u + 0x7fffu + ((u >> 16) & 1u)) >> 16);  // RNE
}
__device__ __forceinline__ float bf2f(ushort_t h) {
  return __uint_as_float(((unsigned)h) << 16);
}

// ---------------- block reduction helpers (256-thread blocks) ----------------
__device__ __forceinline__ float blockReduceSum256(float v, float* red) {
  #pragma unroll
  for (int o = 32; o; o >>= 1) v += __shfl_xor(v, o);
  int wid = threadIdx.x >> 6, lane = threadIdx.x & 63;
  if (lane == 0) red[wid] = v;
  __syncthreads();
  v = red[0] + red[1] + red[2] + red[3];
  __syncthreads();
  return v;
}
__device__ __forceinline__ float blockReduceMax256(float v, float* red) {
  #pragma unroll
  for (int o = 32; o; o >>= 1) v = fmaxf(v, __shfl_xor(v, o));
  int wid = threadIdx.x >> 6, lane = threadIdx.x & 63;
  if (lane == 0) red[wid] = v;
  __syncthreads();
  v = fmaxf(fmaxf(red[0], red[1]), fmaxf(red[2], red[3]));
  __syncthreads();
  return v;
}

// ===== 1-pass bf16 MFMA GEMM, 128x128 tile, raw-barrier async pipeline =====
// C = A @ B^T (+bias). A: bf16. B: bf16 (BF16B) or fp32 (converted in staging).
// M = 512 exact (grid.y=4). N ragged (epilogue-guarded). K%32==0; kChunk%32==0.
// Split-K via z; ZFAST: z = blockIdx.x (XCD/L2 locality for vin).
// LDS: 16B unit (row,q) at unit-idx (row>>4)*64 + q*16 + (row&15)
//   -> frag read addr = base + 16*lane (conflict-free; SQ_LDS_BANK_CONFLICT==0 R6-R10).
// Pipeline (T3/T4-minimal): ds_write buf[t&1] from regs R; issue next loads (R);
// asm lgkmcnt(0); RAW s_barrier (no vmcnt drain -> loads stay in flight); compute.
// Single barrier per k-step: iter t's writes to buf[p] ordered vs iter t-2's reads
// of buf[p] by iter t-1's lgkmcnt(0)+barrier (lgkmcnt drains ds_reads too).
template <bool BF16B, bool BIAS, bool CAUSAL, bool POUT, bool ZFAST>
__global__ __launch_bounds__(256, 2) void glds4(
    const ushort_t* __restrict__ A, const void* __restrict__ Bv,
    const float* __restrict__ bias, float* __restrict__ C, ushort_t* __restrict__ Ch,
    int N, int K, int lda, int ldb, int ldc,
    int kChunk, long aZ, long bZ, long cZ)
{
  const int z  = ZFAST ? blockIdx.x : blockIdx.z;
  const int m0 = blockIdx.y * 128;
  const int n0 = (ZFAST ? blockIdx.z : blockIdx.x) * 128;
  if (CAUSAL && n0 > m0 + 127) return;   // tile fully above diagonal (block-uniform)
  __shared__ ushort_t sA[2][4096], sB[2][4096];   // 2 bufs x 512 units x 8 bf16
  const int tid = threadIdx.x;
  const int kBeg = kChunk ? z * kChunk : 0;
  const int kEnd = kChunk ? kBeg + kChunk : K;
  A += (size_t)z * aZ;
  const ushort_t* Bh = (const ushort_t*)Bv;
  const float*    Bf = (const float*)Bv;
  if (BF16B) Bh += (size_t)z * bZ; else Bf += (size_t)z * bZ;
  C += (size_t)z * cZ;
  if (POUT) Ch += (size_t)z * cZ;

  // staging map: thread t -> unit t (rows 0-63 region) and t+256 (rows 64-127)
  const int r0 = ((tid >> 6) << 4) | (tid & 15);   // unit t -> row
  const int q0 = (tid >> 4) & 3;                   // k-quarter within 32
  const int r1 = r0 + 64;
  const ushort_t* pA0 = A + (size_t)(m0 + r0) * lda + (q0 << 3);
  const ushort_t* pA1 = A + (size_t)(m0 + r1) * lda + (q0 << 3);
  const int gn0 = n0 + r0, gn1 = n0 + r1;
  const bool bok0 = gn0 < N, bok1 = gn1 < N;
  const ushort_t* pB0h = Bh + (size_t)gn0 * ldb + (q0 << 3);
  const ushort_t* pB1h = Bh + (size_t)gn1 * ldb + (q0 << 3);
  const float*    pB0f = Bf + (size_t)gn0 * ldb + (q0 << 3);
  const float*    pB1f = Bf + (size_t)gn1 * ldb + (q0 << 3);

  // waves 2x2, each 64x64
  const int lane = tid & 63;
  const int wrb = (tid >> 7) & 1;
  const int wcb = (tid >> 6) & 1;
  const int fr = lane & 15, fq = lane >> 4;

  f32x4 acc[4][4] = {};
  const short8 z8 = {0, 0, 0, 0, 0, 0, 0, 0};
  const float4 z4 = make_float4(0.f, 0.f, 0.f, 0.f);

  // one named register prefetch set (loads survive the raw barrier)
  short8 ra0, ra1, rb0, rb1; float4 rf0, rf1, rf2, rf3;

#define LOADR(KK) { ra0 = *(const short8*)(pA0 + (KK)); ra1 = *(const short8*)(pA1 + (KK)); \
  if (BF16B) { rb0 = bok0 ? *(const short8*)(pB0h + (KK)) : z8;                             \
               rb1 = bok1 ? *(const short8*)(pB1h + (KK)) : z8; }                           \
  else { rf0 = bok0 ? *(const float4*)(pB0f + (KK)) : z4;                                   \
         rf1 = bok0 ? *(const float4*)(pB0f + (KK) + 4) : z4;                               \
         rf2 = bok1 ? *(const float4*)(pB1f + (KK)) : z4;                                   \
         rf3 = bok1 ? *(const float4*)(pB1f + (KK) + 4) : z4; } }

#define STAGER(BUF) { *(short8*)&sA[BUF][tid << 3] = ra0;                                   \
  *(short8*)&sA[BUF][(tid + 256) << 3] = ra1;                                               \
  if (BF16B) { *(short8*)&sB[BUF][tid << 3] = rb0;                                          \
               *(short8*)&sB[BUF][(tid + 256) << 3] = rb1; }                                \
  else { short8 s0_, s1_;                                                                   \
    _Pragma("unroll") for (int j = 0; j < 4; ++j) {                                         \
      s0_[j] = (short)f2bf(rf0[j]); s0_[j + 4] = (short)f2bf(rf1[j]);                       \
      s1_[j] = (short)f2bf(rf2[j]); s1_[j + 4] = (short)f2bf(rf3[j]); }                     \
    *(short8*)&sB[BUF][tid << 3] = s0_; *(short8*)&sB[BUF][(tid + 256) << 3] = s1_; } }

#define COMPUTE(BUF) { short8 fa[4], fb[4];                                                 \
  _Pragma("unroll") for (int f = 0; f < 4; ++f)                                             \
    fa[f] = *(const short8*)&sA[BUF][((((wrb << 2) + f) << 9) | (lane << 3))];              \
  _Pragma("unroll") for (int g = 0; g < 4; ++g)                                             \
    fb[g] = *(const short8*)&sB[BUF][((((wcb << 2) + g) << 9) | (lane << 3))];              \
  _Pragma("unroll") for (int f = 0; f < 4; ++f)                                             \
    _Pragma("unroll") for (int g = 0; g < 4; ++g)                                           \
      acc[f][g] = __builtin_amdgcn_mfma_f32_16x16x32_bf16(fa[f], fb[g], acc[f][g], 0, 0, 0); }

  // prologue: issue first tile's loads
  LOADR(kBeg);

  const int nt = (kEnd - kBeg) >> 5;
  for (int t = 0; t < nt; ++t) {
    const int cur = t & 1;
    STAGER(cur);                                   // compiler waits vmcnt for R only
    if (t + 1 < nt) LOADR(kBeg + ((t + 1) << 5));  // in flight across the barrier
    asm volatile("s_waitcnt lgkmcnt(0)" ::: "memory");  // ds_writes (and prior ds_reads) done
    __builtin_amdgcn_s_barrier();                  // raw barrier: NO vmcnt drain
    __builtin_amdgcn_sched_barrier(0);             // keep ds_reads below the barrier
    COMPUTE(cur);
    asm volatile("" ::: "memory");
  }

#undef LOADR
#undef STAGER
#undef COMPUTE

  // ---- epilogue: C/D layout col=lane&15, row=(lane>>4)*4+reg ----
  #pragma unroll
  for (int f = 0; f < 4; ++f) {
    const int gm = m0 + (wrb << 6) + f * 16 + fq * 4;
    #pragma unroll
    for (int g = 0; g < 4; ++g) {
      const int gn = n0 + (wcb << 6) + g * 16 + fr;
      if (gn < N) {
        #pragma unroll
        for (int i = 0; i < 4; ++i) {
          float v = acc[f][g][i];
          if (BIAS) v += bias[gn];
          const size_t o = (size_t)(gm + i) * ldc + gn;
          if (POUT) Ch[o] = f2bf(v);
          else      C[o] = v;
        }
      }
    }
  }
}

// ---------------- split-K combine: outh = bf16(sum_z part[z] + bias (+relu)) ----------------
template <bool RELU>
__global__ __launch_bounds__(256) void combine(
    const float* __restrict__ part, const float* __restrict__ bias,
    ushort_t* __restrict__ outh, int nz, long zstride, int total4, int N4)
{
  const int i = blockIdx.x * 256 + threadIdx.x;
  if (i >= total4) return;
  float4 s = ((const float4*)bias)[i % N4];
  for (int z = 0; z < nz; ++z) {
    float4 p = ((const float4*)(part + (size_t)z * zstride))[i];
    s.x += p.x; s.y += p.y; s.z += p.z; s.w += p.w;
  }
  if (RELU) {
    s.x = fmaxf(s.x, 0.f); s.y = fmaxf(s.y, 0.f);
    s.z = fmaxf(s.z, 0.f); s.w = fmaxf(s.w, 0.f);
  }
  ((ushort4*)outh)[i] = make_ushort4(f2bf(s.x), f2bf(s.y), f2bf(s.z), f2bf(s.w));
}

// ---------------- fused split-K combine + residual + LayerNorm ----------------
__global__ __launch_bounds__(256) void ln_parts(
    const float* __restrict__ part, int nz, const float* __restrict__ bias,
    float* __restrict__ x, ushort_t* __restrict__ xh,
    const float* __restrict__ g, const float* __restrict__ b)
{
  const int t = blockIdx.x, tid = threadIdx.x;
  float4 y = ((const float4*)(x + (size_t)t * 1024))[tid];
  float4 s = ((const float4*)bias)[tid];
  for (int z = 0; z < nz; ++z) {
    float4 p = ((const float4*)(part + (size_t)z * 524288 + (size_t)t * 1024))[tid];
    s.x += p.x; s.y += p.y; s.z += p.z; s.w += p.w;
  }
  y.x += s.x; y.y += s.y; y.z += s.z; y.w += s.w;
  __shared__ float red[4];
  float sum = blockReduceSum256(y.x + y.y + y.z + y.w, red);
  const float m = sum * (1.f / 1024.f);
  float dx = y.x - m, dy = y.y - m, dz = y.z - m, dw = y.w - m;
  float q = blockReduceSum256(dx * dx + dy * dy + dz * dz + dw * dw, red);
  const float rs = rsqrtf(q * (1.f / 1024.f) + 1e-5f);
  float4 gg = ((const float4*)g)[tid], bb = ((const float4*)b)[tid];
  float4 o;
  o.x = dx * rs * gg.x + bb.x;
  o.y = dy * rs * gg.y + bb.y;
  o.z = dz * rs * gg.z + bb.z;
  o.w = dw * rs * gg.w + bb.w;
  ((float4*)(x + (size_t)t * 1024))[tid] = o;
  ((ushort4*)xh)[t * 256 + tid] = make_ushort4(f2bf(o.x), f2bf(o.y), f2bf(o.z), f2bf(o.w));
}

// ---------------- vectorized fp32 -> bf16 conversions ----------------
__global__ __launch_bounds__(256) void cvt_flat(
    const float* __restrict__ src, ushort_t* __restrict__ dst, int total4)
{
  const int i = blockIdx.x * 256 + threadIdx.x;
  if (i >= total4) return;
  float4 v = ((const float4*)src)[i];
  ((ushort4*)dst)[i] = make_ushort4(f2bf(v.x), f2bf(v.y), f2bf(v.z), f2bf(v.w));
}

__global__ __launch_bounds__(256) void cvt_pad(
    const float* __restrict__ src, ushort_t* __restrict__ dst,
    int Csrc, int Cdst4, int total4)
{
  const int i = blockIdx.x * 256 + threadIdx.x;
  if (i >= total4) return;
  const int r = i / Cdst4;
  const int c = (i - r * Cdst4) << 2;
  const float* s = src + (size_t)r * Csrc + c;
  ushort4 o = make_ushort4(0, 0, 0, 0);
  if (c + 3 < Csrc) {
    o = make_ushort4(f2bf(s[0]), f2bf(s[1]), f2bf(s[2]), f2bf(s[3]));
  } else {
    if (c + 0 < Csrc) o.x = f2bf(s[0]);
    if (c + 1 < Csrc) o.y = f2bf(s[1]);
    if (c + 2 < Csrc) o.z = f2bf(s[2]);
    if (c + 3 < Csrc) o.w = f2bf(s[3]);
  }
  ((ushort4*)dst)[i] = o;
}

__global__ __launch_bounds__(256) void prep_vin_v(
    const float* __restrict__ vertice, const float* __restrict__ tmpl,
    ushort_t* __restrict__ dst, int total4)
{
  const int i = blockIdx.x * 256 + threadIdx.x;
  if (i >= total4) return;
  const int C4 = KVIN >> 2;
  const int t = i / C4;
  const int c = (i - t * C4) << 2;
  ushort4 o = make_ushort4(0, 0, 0, 0);
  if (t > 0) {
    const float* s = vertice + (size_t)(t - 1) * 15069 + c;
    if (c + 3 < 15069) {
      o = make_ushort4(f2bf(s[0] - tmpl[c]),     f2bf(s[1] - tmpl[c + 1]),
                       f2bf(s[2] - tmpl[c + 2]), f2bf(s[3] - tmpl[c + 3]));
    } else {
      if (c + 0 < 15069) o.x = f2bf(s[0] - tmpl[c]);
      if (c + 1 < 15069) o.y = f2bf(s[1] - tmpl[c + 1]);
      if (c + 2 < 15069) o.z = f2bf(s[2] - tmpl[c + 2]);
      if (c + 3 < 15069) o.w = f2bf(s[3] - tmpl[c + 3]);
    }
  }
  ((ushort4*)dst)[i] = o;
}

__global__ void prep_bias2(const float* __restrict__ one_hot, const float* __restrict__ W_obj,
                           const float* __restrict__ b_vm, float* __restrict__ bias2) {
  int d = blockIdx.x * 256 + threadIdx.x;
  if (d < 1024) {
    float s = 0.f;
    #pragma unroll
    for (int j = 0; j < 8; ++j) s += one_hot[j] * W_obj[d * 8 + j];
    bias2[d] = b_vm[d] + s;
  }
}

__global__ void prep_bias3(const float* __restrict__ b_vr, const float* __restrict__ tmpl,
                           float* __restrict__ bias3, int n) {
  int v = blockIdx.x * 256 + threadIdx.x;
  if (v < n) bias3[v] = b_vr[v] + tmpl[v];
}

// sum 16 vin split-K partials + bias2 + PE -> x (f32 + bf16)
__global__ __launch_bounds__(256) void reduce_pe(const float* __restrict__ part,
                                                 const float* __restrict__ bias2,
                                                 float* __restrict__ x,
                                                 ushort_t* __restrict__ xh) {
  const int t = blockIdx.x;
  const float PECOEF = -9.210340371976184f / 512.f;  // -ln(10000)/512
  const int p = t % 25;
  for (int d = threadIdx.x; d < 1024; d += 256) {
    float s = bias2[d];
    #pragma unroll
    for (int z = 0; z < 16; ++z) s += part[(size_t)z * 524288 + (size_t)t * 1024 + d];
    float arg = (float)p * expf((float)(d >> 1) * PECOEF);
    s += (d & 1) ? cosf(arg) : sinf(arg);
    const size_t idx = (size_t)t * 1024 + d;
    x[idx] = s;
    xh[idx] = f2bf(s);
  }
}

// V transpose from qkv split-K parts: vth[d][s] = bf16(sum_z part[z][s][2048+d] + bias)
__global__ __launch_bounds__(256) void vT_parts(const float* __restrict__ part,
                                                const float* __restrict__ bias,
                                                ushort_t* __restrict__ vth) {
  __shared__ float tile[32][33];
  const int s0 = blockIdx.x * 32, d0 = blockIdx.y * 32;
  const int tx = threadIdx.x & 31, ty = threadIdx.x >> 5;  // 32 x 8
  for (int r = ty; r < 32; r += 8) {
    float v = bias[2048 + d0 + tx];
    #pragma unroll
    for (int z = 0; z < 4; ++z)
      v += part[(size_t)z * 1572864 + (size_t)(s0 + r) * 3072 + 2048 + d0 + tx];
    tile[r][tx] = v;
  }
  __syncthreads();
  for (int r = ty; r < 32; r += 8)
    vth[(size_t)(d0 + r) * 512 + s0 + tx] = f2bf(tile[tx][r]);
}

// row softmax with ALIBI + causal; reads raw scores f32, writes attn bf16
__global__ __launch_bounds__(256) void softmax_alibi(const float* __restrict__ scores,
                                                     ushort_t* __restrict__ ah) {
  const int i = blockIdx.x, h = blockIdx.y;
  const size_t rb = ((size_t)h * 512 + i) * 512;
  const float* row = scores + rb;
  const int tid = threadIdx.x;
  const int len = i + 1;
  const float sl = exp2f(-2.f * (float)(h + 1));
  const int j0 = tid, j1 = tid + 256;
  float v0 = -INFINITY, v1 = -INFINITY;
  if (j0 < len) v0 = row[j0] * 0.0625f - sl * (float)((i - j0) / 25);
  if (j1 < len) v1 = row[j1] * 0.0625f - sl * (float)((i - j1) / 25);
  __shared__ float red[4];
  float m = blockReduceMax256(fmaxf(v0, v1), red);
  float e0 = (j0 < len) ? expf(v0 - m) : 0.f;
  float e1 = (j1 < len) ? expf(v1 - m) : 0.f;
  float s = blockReduceSum256(e0 + e1, red);
  float inv = 1.f / s;
  ah[rb + j0] = f2bf(e0 * inv);
  ah[rb + j1] = f2bf(e1 * inv);
}

// ---------------- host-side launch ----------------
extern "C" void kernel_launch(void* const* d_in, const int* in_sizes, int n_in,
                              void* d_out, int out_size, void* d_ws, size_t ws_size,
                              hipStream_t stream) {
  const float* audio   = (const float*)d_in[0];
  const float* vertice = (const float*)d_in[1];
  const float* tmpl    = (const float*)d_in[2];
  const float* one_hot = (const float*)d_in[3];
  const float* W_af    = (const float*)d_in[4];
  const float* b_af    = (const float*)d_in[5];
  const float* W_vm    = (const float*)d_in[6];
  const float* b_vm    = (const float*)d_in[7];
  const float* W_obj   = (const float*)d_in[8];
  const float* Wqkv_sa = (const float*)d_in[9];
  const float* bqkv_sa = (const float*)d_in[10];
  const float* Wo_sa   = (const float*)d_in[11];
  const float* bo_sa   = (const float*)d_in[12];
  const float* Wqkv_ca = (const float*)d_in[13];
  const float* bqkv_ca = (const float*)d_in[14];
  const float* Wo_ca   = (const float*)d_in[15];
  const float* bo_ca   = (const float*)d_in[16];
  const float* W1      = (const float*)d_in[17];
  const float* b1      = (const float*)d_in[18];
  const float* W2      = (const float*)d_in[19];
  const float* b2      = (const float*)d_in[20];
  const float* g1      = (const float*)d_in[21];
  const float* be1     = (const float*)d_in[22];
  const float* g2      = (const float*)d_in[23];
  const float* be2     = (const float*)d_in[24];
  const float* g3      = (const float*)d_in[25];
  const float* be3     = (const float*)d_in[26];
  const float* W_vr    = (const float*)d_in[27];
  const float* b_vr    = (const float*)d_in[28];
  float* out = (float*)d_out;

  // ---- workspace carve (floats), total ~100 MB ----
  float* base = (float*)d_ws;
  float* apF    = base;                  // 512*15360 us  = 3,932,160 fl
  float* wvmF   = apF + 3932160;         // 1024*15360 us = 7,864,320 fl (Wvm, then Wvr after vin)
  float* part   = wvmF + 7864320;        // 16*524288     = 8,388,608 fl
  float* x      = part + 8388608;        // 524,288
  float* xhF    = x + 524288;            // 262,144 (512*1024 us)
  float* audF   = xhF + 262144;          // 196,608 (512*768 us)
  float* hidF   = audF + 196608;         // 262,144
  float* qkvF   = hidF + 262144;         // 786,432 (512*3072 us)
  float* vtF    = qkvF + 786432;         // 262,144 (1024*512 us)
  float* scores = vtF + 262144;          // 1,048,576
  float* attF   = scores + 1048576;      // 524,288 (4*512*512 us)
  float* ctxF   = attF + 524288;         // 262,144
  float* cvF    = ctxF + 262144;         // 262,144
  float* h1F    = cvF + 262144;          // 524,288 (512*2048 us)
  float* bias2  = h1F + 524288;          // 1,024
  float* bias3  = bias2 + 1024;          // 15,072

  ushort_t* Aph  = (ushort_t*)apF;
  ushort_t* Wvmh = (ushort_t*)wvmF;
  ushort_t* Wvrh = (ushort_t*)wvmF;      // alias: Wvm dead after vin GEMM
  ushort_t* xh   = (ushort_t*)xhF;
  ushort_t* audh = (ushort_t*)audF;
  ushort_t* hidh = (ushort_t*)hidF;
  ushort_t* qkvh = (ushort_t*)qkvF;
  ushort_t* vth  = (ushort_t*)vtF;
  ushort_t* atth = (ushort_t*)attF;
  ushort_t* ctxh = (ushort_t*)ctxF;
  ushort_t* cvh  = (ushort_t*)cvF;
  ushort_t* h1h  = (ushort_t*)h1F;

  // ---- prep (all vectorized) ----
  prep_bias2<<<4, 256, 0, stream>>>(one_hot, W_obj, b_vm, bias2);
  prep_bias3<<<(15069 + 255) / 256, 256, 0, stream>>>(b_vr, tmpl, bias3, 15069);
  prep_vin_v<<<7680, 256, 0, stream>>>(vertice, tmpl, Aph, 512 * (KVIN / 4));
  cvt_pad<<<15360, 256, 0, stream>>>(W_vm, Wvmh, 15069, KVIN / 4, 1024 * (KVIN / 4));

  // ---- vin = Ap @ Wvm^T  (split-K x16, z-fastest for XCD/L2 locality) ----
  glds4<true, false, false, false, true><<<dim3(16, 4, 8), 256, 0, stream>>>(
      Aph, Wvmh, nullptr, part, nullptr,
      1024, KVIN, KVIN, KVIN, 1024, 960, 0, 0, 524288);
  reduce_pe<<<512, 256, 0, stream>>>(part, bias2, x, xh);

  // Wvr bf16 (reuse wvm region; Wvm dead after vin GEMM above)
  cvt_flat<<<15069, 256, 0, stream>>>(W_vr, Wvrh, 15069 * 256);

  // ---- hidden = audio @ W_af^T + b_af ----
  cvt_flat<<<384, 256, 0, stream>>>(audio, audh, 512 * 192);
  glds4<false, false, false, false, false><<<dim3(8, 4, 6), 256, 0, stream>>>(
      audh, W_af, nullptr, part, nullptr,
      1024, 768, 768, 768, 1024, 128, 0, 0, 524288);
  combine<false><<<512, 256, 0, stream>>>(part, b_af, hidh, 6, 524288, 131072, 256);

  // ---- self attention ----
  glds4<false, false, false, false, false><<<dim3(24, 4, 4), 256, 0, stream>>>(
      xh, Wqkv_sa, nullptr, part, nullptr,
      3072, 1024, 1024, 1024, 3072, 256, 0, 0, 1572864);
  combine<false><<<1536, 256, 0, stream>>>(part, bqkv_sa, qkvh, 4, 1572864, 393216, 768);
  vT_parts<<<dim3(16, 32), 256, 0, stream>>>(part, bqkv_sa, vth);
  // scores[h] = q_h @ k_h^T : z = head via kChunk=256 (causal tiles only)
  glds4<true, false, true, false, false><<<dim3(4, 4, 4), 256, 0, stream>>>(
      qkvh, qkvh + 1024, nullptr, scores, nullptr,
      512, 1024, 3072, 3072, 512, 256, 0, 0, 262144);
  softmax_alibi<<<dim3(512, 4), 256, 0, stream>>>(scores, atth);
  // ctx[h] = attn_h @ vT_h^T, bf16 out directly
  glds4<true, false, false, true, false><<<dim3(2, 4, 4), 256, 0, stream>>>(
      atth, vth, nullptr, nullptr, ctxh,
      256, 512, 512, 512, 1024, 0, 262144, 131072, 256);
  // out proj + LN
  glds4<false, false, false, false, false><<<dim3(8, 4, 8), 256, 0, stream>>>(
      ctxh, Wo_sa, nullptr, part, nullptr,
      1024, 1024, 1024, 1024, 1024, 128, 0, 0, 524288);
  ln_parts<<<512, 256, 0, stream>>>(part, 8, bo_sa, x, xh, g1, be1);

  // ---- cross attention: bool mask == identity -> V then O projection ----
  glds4<false, false, false, false, false><<<dim3(8, 4, 8), 256, 0, stream>>>(
      hidh, Wqkv_ca + (size_t)2048 * 1024, nullptr, part, nullptr,
      1024, 1024, 1024, 1024, 1024, 128, 0, 0, 524288);
  combine<false><<<512, 256, 0, stream>>>(part, bqkv_ca + 2048, cvh, 8, 524288, 131072, 256);
  glds4<false, false, false, false, false><<<dim3(8, 4, 8), 256, 0, stream>>>(
      cvh, Wo_ca, nullptr, part, nullptr,
      1024, 1024, 1024, 1024, 1024, 128, 0, 0, 524288);
  ln_parts<<<512, 256, 0, stream>>>(part, 8, bo_ca, x, xh, g2, be2);

  // ---- feed forward ----
  glds4<false, false, false, false, false><<<dim3(16, 4, 4), 256, 0, stream>>>(
      xh, W1, nullptr, part, nullptr,
      2048, 1024, 1024, 1024, 2048, 256, 0, 0, 1048576);
  combine<true><<<1024, 256, 0, stream>>>(part, b1, h1h, 4, 1048576, 262144, 512);
  glds4<false, false, false, false, false><<<dim3(8, 4, 8), 256, 0, stream>>>(
      h1h, W2, nullptr, part, nullptr,
      1024, 2048, 2048, 2048, 1024, 256, 0, 0, 524288);
  ln_parts<<<512, 256, 0, stream>>>(part, 8, b2, x, xh, g3, be3);

  // ---- final projection: out = x @ W_vr^T + (b_vr + tmpl)  (pre-split bf16 B) ----
  glds4<true, true, false, false, false><<<dim3(118, 4, 1), 256, 0, stream>>>(
      xh, Wvrh, bias3, out, nullptr,
      15069, 1024, 1024, 1024, 15069, 0, 0, 0, 0);
}

// Round 12
// 346.135 us; speedup vs baseline: 1.2607x; 1.0334x over previous
//
#include <hip/hip_runtime.h>
#include <math.h>

typedef __attribute__((ext_vector_type(8))) short short8;
typedef __attribute__((ext_vector_type(4))) float f32x4;
typedef unsigned short ushort_t;

#define KVIN 15360   // 15069 padded to 960*16 (split-K x16, K%32==0)

__device__ __forceinline__ ushort_t f2bf(float f) {
  unsigned u = __float_as_uint(f);
  return (ushort_t)((u + 0x7fffu + ((u >> 16) & 1u)) >> 16);  // RNE
}
__device__ __forceinline__ float bf2f(ushort_t h) {
  return __uint_as_float(((unsigned)h) << 16);
}

// ---------------- block reduction helpers (256-thread blocks) ----------------
__device__ __forceinline__ float blockReduceSum256(float v, float* red) {
  #pragma unroll
  for (int o = 32; o; o >>= 1) v += __shfl_xor(v, o);
  int wid = threadIdx.x >> 6, lane = threadIdx.x & 63;
  if (lane == 0) red[wid] = v;
  __syncthreads();
  v = red[0] + red[1] + red[2] + red[3];
  __syncthreads();
  return v;
}
__device__ __forceinline__ float blockReduceMax256(float v, float* red) {
  #pragma unroll
  for (int o = 32; o; o >>= 1) v = fmaxf(v, __shfl_xor(v, o));
  int wid = threadIdx.x >> 6, lane = threadIdx.x & 63;
  if (lane == 0) red[wid] = v;
  __syncthreads();
  v = fmaxf(fmaxf(red[0], red[1]), fmaxf(red[2], red[3]));
  __syncthreads();
  return v;
}

// ===== 1-pass bf16 MFMA GEMM, 128x128 tile, raw-barrier async pipeline =====
// C = A @ B^T (+bias). A: bf16. B: bf16 (BF16B) or fp32 (converted in staging).
// N ragged (epilogue-guarded). K%32==0; kChunk%32==0.
// BIASM: 0 none, 1 +bias[gn], 2 +bias[gn]+biasB[gn].
// GMODE: 0 grid (nTile, mTile, z); 1 z-fastest (z, mTile, nTile);
//        2 XCD n-swizzle 1-D grid: 4 m-tiles of one n-panel share an XCD (L2 B reuse).
// ZDIV: 0 -> kBeg = z*kChunk, A/B offset by z (legacy). >0 -> batch=z/ZDIV (A/B offset),
//        ks=z%ZDIV (kBeg=ks*kChunk); C always offset by z*cZ (per-z partials).
// LDS: 16B unit (row,q) at unit-idx (row>>4)*64 + q*16 + (row&15)
//   -> frag read addr = base + 16*lane (conflict-free; SQ_LDS_BANK_CONFLICT==0 R6-R11).
template <bool BF16B, int BIASM, bool CAUSAL, int GMODE, int ZDIV>
__global__ __launch_bounds__(256, 2) void glds5(
    const ushort_t* __restrict__ A, const void* __restrict__ Bv,
    const float* __restrict__ bias, const float* __restrict__ biasB,
    float* __restrict__ C,
    int N, int K, int lda, int ldb, int ldc,
    int kChunk, long aZ, long bZ, long cZ)
{
  int z, m0, n0;
  if (GMODE == 2) {
    const int id = blockIdx.x, u = id & 7, v = id >> 3;
    m0 = (v & 3) * 128;
    n0 = (((v >> 2) << 3) + u) * 128;
    z = 0;
    if (n0 >= N) return;
  } else if (GMODE == 1) {
    z = blockIdx.x; m0 = blockIdx.y * 128; n0 = blockIdx.z * 128;
  } else {
    z = blockIdx.z; m0 = blockIdx.y * 128; n0 = blockIdx.x * 128;
  }
  if (CAUSAL && n0 > m0 + 127) return;   // tile fully above diagonal (block-uniform)
  __shared__ ushort_t sA[2][4096], sB[2][4096];   // 2 bufs x 512 units x 8 bf16
  const int tid = threadIdx.x;
  const int ks = ZDIV ? (z % ZDIV) : z;
  const int zb = ZDIV ? (z / ZDIV) : z;
  const int kBeg = kChunk ? ks * kChunk : 0;
  const int kEnd = kChunk ? kBeg + kChunk : K;
  A += (size_t)zb * aZ;
  const ushort_t* Bh = (const ushort_t*)Bv;
  const float*    Bf = (const float*)Bv;
  if (BF16B) Bh += (size_t)zb * bZ; else Bf += (size_t)zb * bZ;
  C += (size_t)z * cZ;

  // staging map: thread t -> unit t (rows 0-63 region) and t+256 (rows 64-127)
  const int r0 = ((tid >> 6) << 4) | (tid & 15);   // unit t -> row
  const int q0 = (tid >> 4) & 3;                   // k-quarter within 32
  const int r1 = r0 + 64;
  const ushort_t* pA0 = A + (size_t)(m0 + r0) * lda + (q0 << 3);
  const ushort_t* pA1 = A + (size_t)(m0 + r1) * lda + (q0 << 3);
  const int gn0 = n0 + r0, gn1 = n0 + r1;
  const bool bok0 = gn0 < N, bok1 = gn1 < N;
  const ushort_t* pB0h = Bh + (size_t)gn0 * ldb + (q0 << 3);
  const ushort_t* pB1h = Bh + (size_t)gn1 * ldb + (q0 << 3);
  const float*    pB0f = Bf + (size_t)gn0 * ldb + (q0 << 3);
  const float*    pB1f = Bf + (size_t)gn1 * ldb + (q0 << 3);

  // waves 2x2, each 64x64
  const int lane = tid & 63;
  const int wrb = (tid >> 7) & 1;
  const int wcb = (tid >> 6) & 1;
  const int fr = lane & 15, fq = lane >> 4;

  f32x4 acc[4][4] = {};
  const short8 z8 = {0, 0, 0, 0, 0, 0, 0, 0};
  const float4 z4 = make_float4(0.f, 0.f, 0.f, 0.f);

  short8 ra0, ra1, rb0, rb1; float4 rf0, rf1, rf2, rf3;

#define LOADR(KK) { ra0 = *(const short8*)(pA0 + (KK)); ra1 = *(const short8*)(pA1 + (KK)); \
  if (BF16B) { rb0 = bok0 ? *(const short8*)(pB0h + (KK)) : z8;                             \
               rb1 = bok1 ? *(const short8*)(pB1h + (KK)) : z8; }                           \
  else { rf0 = bok0 ? *(const float4*)(pB0f + (KK)) : z4;                                   \
         rf1 = bok0 ? *(const float4*)(pB0f + (KK) + 4) : z4;                               \
         rf2 = bok1 ? *(const float4*)(pB1f + (KK)) : z4;                                   \
         rf3 = bok1 ? *(const float4*)(pB1f + (KK) + 4) : z4; } }

#define STAGER(BUF) { *(short8*)&sA[BUF][tid << 3] = ra0;                                   \
  *(short8*)&sA[BUF][(tid + 256) << 3] = ra1;                                               \
  if (BF16B) { *(short8*)&sB[BUF][tid << 3] = rb0;                                          \
               *(short8*)&sB[BUF][(tid + 256) << 3] = rb1; }                                \
  else { short8 s0_, s1_;                                                                   \
    _Pragma("unroll") for (int j = 0; j < 4; ++j) {                                         \
      s0_[j] = (short)f2bf(rf0[j]); s0_[j + 4] = (short)f2bf(rf1[j]);                       \
      s1_[j] = (short)f2bf(rf2[j]); s1_[j + 4] = (short)f2bf(rf3[j]); }                     \
    *(short8*)&sB[BUF][tid << 3] = s0_; *(short8*)&sB[BUF][(tid + 256) << 3] = s1_; } }

#define COMPUTE(BUF) { short8 fa[4], fb[4];                                                 \
  _Pragma("unroll") for (int f = 0; f < 4; ++f)                                             \
    fa[f] = *(const short8*)&sA[BUF][((((wrb << 2) + f) << 9) | (lane << 3))];              \
  _Pragma("unroll") for (int g = 0; g < 4; ++g)                                             \
    fb[g] = *(const short8*)&sB[BUF][((((wcb << 2) + g) << 9) | (lane << 3))];              \
  _Pragma("unroll") for (int f = 0; f < 4; ++f)                                             \
    _Pragma("unroll") for (int g = 0; g < 4; ++g)                                           \
      acc[f][g] = __builtin_amdgcn_mfma_f32_16x16x32_bf16(fa[f], fb[g], acc[f][g], 0, 0, 0); }

  LOADR(kBeg);
  const int nt = (kEnd - kBeg) >> 5;
  for (int t = 0; t < nt; ++t) {
    const int cur = t & 1;
    STAGER(cur);                                   // compiler waits vmcnt for R only
    if (t + 1 < nt) LOADR(kBeg + ((t + 1) << 5));  // in flight across the barrier
    asm volatile("s_waitcnt lgkmcnt(0)" ::: "memory");
    __builtin_amdgcn_s_barrier();                  // raw barrier: no vmcnt drain
    __builtin_amdgcn_sched_barrier(0);
    COMPUTE(cur);
    asm volatile("" ::: "memory");
  }

#undef LOADR
#undef STAGER
#undef COMPUTE

  // ---- epilogue: C/D layout col=lane&15, row=(lane>>4)*4+reg ----
  #pragma unroll
  for (int f = 0; f < 4; ++f) {
    const int gm = m0 + (wrb << 6) + f * 16 + fq * 4;
    #pragma unroll
    for (int g = 0; g < 4; ++g) {
      const int gn = n0 + (wcb << 6) + g * 16 + fr;
      if (gn < N) {
        #pragma unroll
        for (int i = 0; i < 4; ++i) {
          float v = acc[f][g][i];
          if (BIASM >= 1) v += bias[gn];
          if (BIASM >= 2) v += biasB[gn];
          C[(size_t)(gm + i) * ldc + gn] = v;
        }
      }
    }
  }
}

// ---------------- split-K combine: outh = bf16(sum_z part[z] + bias (+relu)) ----------------
template <bool RELU>
__global__ __launch_bounds__(256) void combine(
    const float* __restrict__ part, const float* __restrict__ bias,
    ushort_t* __restrict__ outh, int nz, long zstride, int total4, int N4)
{
  const int i = blockIdx.x * 256 + threadIdx.x;
  if (i >= total4) return;
  float4 s = ((const float4*)bias)[i % N4];
  for (int z = 0; z < nz; ++z) {
    float4 p = ((const float4*)(part + (size_t)z * zstride))[i];
    s.x += p.x; s.y += p.y; s.z += p.z; s.w += p.w;
  }
  if (RELU) {
    s.x = fmaxf(s.x, 0.f); s.y = fmaxf(s.y, 0.f);
    s.z = fmaxf(s.z, 0.f); s.w = fmaxf(s.w, 0.f);
  }
  ((ushort4*)outh)[i] = make_ushort4(f2bf(s.x), f2bf(s.y), f2bf(s.z), f2bf(s.w));
}

// PV combine: ctxh[t][h*256+d] = bf16(sum_{ks<4} pvpart[h*4+ks][t][d])
__global__ __launch_bounds__(256) void combine_pv(
    const float* __restrict__ part, ushort_t* __restrict__ ctxh)
{
  const int t = blockIdx.x, tid = threadIdx.x;
  const int h = tid >> 6, dq = tid & 63;
  float4 s = make_float4(0.f, 0.f, 0.f, 0.f);
  #pragma unroll
  for (int ks = 0; ks < 4; ++ks) {
    float4 p = ((const float4*)(part + (size_t)(h * 4 + ks) * 131072 + (size_t)t * 256))[dq];
    s.x += p.x; s.y += p.y; s.z += p.z; s.w += p.w;
  }
  ((ushort4*)ctxh)[t * 256 + h * 64 + dq] =
      make_ushort4(f2bf(s.x), f2bf(s.y), f2bf(s.z), f2bf(s.w));
}

// ---------------- fused split-K combine + residual + LayerNorm ----------------
__global__ __launch_bounds__(256) void ln_parts(
    const float* __restrict__ part, int nz, const float* __restrict__ bias,
    float* __restrict__ x, ushort_t* __restrict__ xh,
    const float* __restrict__ g, const float* __restrict__ b)
{
  const int t = blockIdx.x, tid = threadIdx.x;
  float4 y = ((const float4*)(x + (size_t)t * 1024))[tid];
  float4 s = ((const float4*)bias)[tid];
  for (int z = 0; z < nz; ++z) {
    float4 p = ((const float4*)(part + (size_t)z * 524288 + (size_t)t * 1024))[tid];
    s.x += p.x; s.y += p.y; s.z += p.z; s.w += p.w;
  }
  y.x += s.x; y.y += s.y; y.z += s.z; y.w += s.w;
  __shared__ float red[4];
  float sum = blockReduceSum256(y.x + y.y + y.z + y.w, red);
  const float m = sum * (1.f / 1024.f);
  float dx = y.x - m, dy = y.y - m, dz = y.z - m, dw = y.w - m;
  float q = blockReduceSum256(dx * dx + dy * dy + dz * dz + dw * dw, red);
  const float rs = rsqrtf(q * (1.f / 1024.f) + 1e-5f);
  float4 gg = ((const float4*)g)[tid], bb = ((const float4*)b)[tid];
  float4 o;
  o.x = dx * rs * gg.x + bb.x;
  o.y = dy * rs * gg.y + bb.y;
  o.z = dz * rs * gg.z + bb.z;
  o.w = dw * rs * gg.w + bb.w;
  ((float4*)(x + (size_t)t * 1024))[tid] = o;
  ((ushort4*)xh)[t * 256 + tid] = make_ushort4(f2bf(o.x), f2bf(o.y), f2bf(o.z), f2bf(o.w));
}

// ---------------- vectorized fp32 -> bf16 conversions ----------------
__global__ __launch_bounds__(256) void cvt_flat(
    const float* __restrict__ src, ushort_t* __restrict__ dst, int total4)
{
  const int i = blockIdx.x * 256 + threadIdx.x;
  if (i >= total4) return;
  float4 v = ((const float4*)src)[i];
  ((ushort4*)dst)[i] = make_ushort4(f2bf(v.x), f2bf(v.y), f2bf(v.z), f2bf(v.w));
}

__global__ __launch_bounds__(256) void cvt_pad(
    const float* __restrict__ src, ushort_t* __restrict__ dst,
    int Csrc, int Cdst4, int total4)
{
  const int i = blockIdx.x * 256 + threadIdx.x;
  if (i >= total4) return;
  const int r = i / Cdst4;
  const int c = (i - r * Cdst4) << 2;
  const float* s = src + (size_t)r * Csrc + c;
  ushort4 o = make_ushort4(0, 0, 0, 0);
  if (c + 3 < Csrc) {
    o = make_ushort4(f2bf(s[0]), f2bf(s[1]), f2bf(s[2]), f2bf(s[3]));
  } else {
    if (c + 0 < Csrc) o.x = f2bf(s[0]);
    if (c + 1 < Csrc) o.y = f2bf(s[1]);
    if (c + 2 < Csrc) o.z = f2bf(s[2]);
    if (c + 3 < Csrc) o.w = f2bf(s[3]);
  }
  ((ushort4*)dst)[i] = o;
}

__global__ __launch_bounds__(256) void prep_vin_v(
    const float* __restrict__ vertice, const float* __restrict__ tmpl,
    ushort_t* __restrict__ dst, int total4)
{
  const int i = blockIdx.x * 256 + threadIdx.x;
  if (i >= total4) return;
  const int C4 = KVIN >> 2;
  const int t = i / C4;
  const int c = (i - t * C4) << 2;
  ushort4 o = make_ushort4(0, 0, 0, 0);
  if (t > 0) {
    const float* s = vertice + (size_t)(t - 1) * 15069 + c;
    if (c + 3 < 15069) {
      o = make_ushort4(f2bf(s[0] - tmpl[c]),     f2bf(s[1] - tmpl[c + 1]),
                       f2bf(s[2] - tmpl[c + 2]), f2bf(s[3] - tmpl[c + 3]));
    } else {
      if (c + 0 < 15069) o.x = f2bf(s[0] - tmpl[c]);
      if (c + 1 < 15069) o.y = f2bf(s[1] - tmpl[c + 1]);
      if (c + 2 < 15069) o.z = f2bf(s[2] - tmpl[c + 2]);
      if (c + 3 < 15069) o.w = f2bf(s[3] - tmpl[c + 3]);
    }
  }
  ((ushort4*)dst)[i] = o;
}

// sum 16 vin split-K partials + (b_vm + style) + PE -> x (f32 + bf16)
__global__ __launch_bounds__(256) void reduce_pe(const float* __restrict__ part,
                                                 const float* __restrict__ one_hot,
                                                 const float* __restrict__ W_obj,
                                                 const float* __restrict__ b_vm,
                                                 float* __restrict__ x,
                                                 ushort_t* __restrict__ xh) {
  const int t = blockIdx.x;
  const float PECOEF = -9.210340371976184f / 512.f;  // -ln(10000)/512
  const int p = t % 25;
  for (int d = threadIdx.x; d < 1024; d += 256) {
    float s = b_vm[d];
    #pragma unroll
    for (int j = 0; j < 8; ++j) s += one_hot[j] * W_obj[d * 8 + j];
    #pragma unroll
    for (int z = 0; z < 16; ++z) s += part[(size_t)z * 524288 + (size_t)t * 1024 + d];
    float arg = (float)p * expf((float)(d >> 1) * PECOEF);
    s += (d & 1) ? cosf(arg) : sinf(arg);
    const size_t idx = (size_t)t * 1024 + d;
    x[idx] = s;
    xh[idx] = f2bf(s);
  }
}

// V transpose from qkv split-K parts: vth[d][s] = bf16(sum_z part[z][s][2048+d] + bias)
__global__ __launch_bounds__(256) void vT_parts(const float* __restrict__ part,
                                                const float* __restrict__ bias,
                                                ushort_t* __restrict__ vth) {
  __shared__ float tile[32][33];
  const int s0 = blockIdx.x * 32, d0 = blockIdx.y * 32;
  const int tx = threadIdx.x & 31, ty = threadIdx.x >> 5;  // 32 x 8
  for (int r = ty; r < 32; r += 8) {
    float v = bias[2048 + d0 + tx];
    #pragma unroll
    for (int z = 0; z < 4; ++z)
      v += part[(size_t)z * 1572864 + (size_t)(s0 + r) * 3072 + 2048 + d0 + tx];
    tile[r][tx] = v;
  }
  __syncthreads();
  for (int r = ty; r < 32; r += 8)
    vth[(size_t)(d0 + r) * 512 + s0 + tx] = f2bf(tile[tx][r]);
}

// row softmax with ALIBI + causal; reads TWO fp32 score partials per head, writes attn bf16
__global__ __launch_bounds__(256) void softmax_alibi(const float* __restrict__ scores,
                                                     ushort_t* __restrict__ ah) {
  const int i = blockIdx.x, h = blockIdx.y;
  const float* r0 = scores + (size_t)(2 * h) * 262144 + (size_t)i * 512;
  const float* r1 = r0 + 262144;
  const size_t rb = ((size_t)h * 512 + i) * 512;
  const int tid = threadIdx.x;
  const int len = i + 1;
  const float sl = exp2f(-2.f * (float)(h + 1));
  const int j0 = tid, j1 = tid + 256;
  float v0 = -INFINITY, v1 = -INFINITY;
  if (j0 < len) v0 = (r0[j0] + r1[j0]) * 0.0625f - sl * (float)((i - j0) / 25);
  if (j1 < len) v1 = (r0[j1] + r1[j1]) * 0.0625f - sl * (float)((i - j1) / 25);
  __shared__ float red[4];
  float m = blockReduceMax256(fmaxf(v0, v1), red);
  float e0 = (j0 < len) ? expf(v0 - m) : 0.f;
  float e1 = (j1 < len) ? expf(v1 - m) : 0.f;
  float s = blockReduceSum256(e0 + e1, red);
  float inv = 1.f / s;
  ah[rb + j0] = f2bf(e0 * inv);
  ah[rb + j1] = f2bf(e1 * inv);
}

// ---------------- host-side launch ----------------
extern "C" void kernel_launch(void* const* d_in, const int* in_sizes, int n_in,
                              void* d_out, int out_size, void* d_ws, size_t ws_size,
                              hipStream_t stream) {
  const float* audio   = (const float*)d_in[0];
  const float* vertice = (const float*)d_in[1];
  const float* tmpl    = (const float*)d_in[2];
  const float* one_hot = (const float*)d_in[3];
  const float* W_af    = (const float*)d_in[4];
  const float* b_af    = (const float*)d_in[5];
  const float* W_vm    = (const float*)d_in[6];
  const float* b_vm    = (const float*)d_in[7];
  const float* W_obj   = (const float*)d_in[8];
  const float* Wqkv_sa = (const float*)d_in[9];
  const float* bqkv_sa = (const float*)d_in[10];
  const float* Wo_sa   = (const float*)d_in[11];
  const float* bo_sa   = (const float*)d_in[12];
  const float* Wqkv_ca = (const float*)d_in[13];
  const float* bqkv_ca = (const float*)d_in[14];
  const float* Wo_ca   = (const float*)d_in[15];
  const float* bo_ca   = (const float*)d_in[16];
  const float* W1      = (const float*)d_in[17];
  const float* b1      = (const float*)d_in[18];
  const float* W2      = (const float*)d_in[19];
  const float* b2      = (const float*)d_in[20];
  const float* g1      = (const float*)d_in[21];
  const float* be1     = (const float*)d_in[22];
  const float* g2      = (const float*)d_in[23];
  const float* be2     = (const float*)d_in[24];
  const float* g3      = (const float*)d_in[25];
  const float* be3     = (const float*)d_in[26];
  const float* W_vr    = (const float*)d_in[27];
  const float* b_vr    = (const float*)d_in[28];
  float* out = (float*)d_out;

  // ---- workspace carve (floats), total ~113 MB ----
  float* base = (float*)d_ws;
  float* apF    = base;                  // 512*15360 us  = 3,932,160 fl
  float* wvmF   = apF + 3932160;         // 1024*15360 us = 7,864,320 fl (Wvm, then Wvr after vin)
  float* part   = wvmF + 7864320;        // 16*524288     = 8,388,608 fl
  float* x      = part + 8388608;        // 524,288
  float* xhF    = x + 524288;            // 262,144 (512*1024 us)
  float* audF   = xhF + 262144;          // 196,608 (512*768 us)
  float* hidF   = audF + 196608;         // 262,144
  float* qkvF   = hidF + 262144;         // 786,432 (512*3072 us)
  float* vtF    = qkvF + 786432;         // 262,144 (1024*512 us)
  float* scores = vtF + 262144;          // 2,097,152 (8 x 512x512 fp32 partials)
  float* attF   = scores + 2097152;      // 524,288 (4*512*512 us)
  float* pvpart = attF + 524288;         // 2,097,152 (16 x 512x256 fp32 partials)
  float* ctxF   = pvpart + 2097152;      // 262,144
  float* cvF    = ctxF + 262144;         // 262,144
  float* h1F    = cvF + 262144;          // 524,288 (512*2048 us)

  ushort_t* Aph  = (ushort_t*)apF;
  ushort_t* Wvmh = (ushort_t*)wvmF;
  ushort_t* Wvrh = (ushort_t*)wvmF;      // alias: Wvm dead after vin GEMM
  ushort_t* xh   = (ushort_t*)xhF;
  ushort_t* audh = (ushort_t*)audF;
  ushort_t* hidh = (ushort_t*)hidF;
  ushort_t* qkvh = (ushort_t*)qkvF;
  ushort_t* vth  = (ushort_t*)vtF;
  ushort_t* atth = (ushort_t*)attF;
  ushort_t* ctxh = (ushort_t*)ctxF;
  ushort_t* cvh  = (ushort_t*)cvF;
  ushort_t* h1h  = (ushort_t*)h1F;

  // ---- prep (all vectorized) ----
  prep_vin_v<<<7680, 256, 0, stream>>>(vertice, tmpl, Aph, 512 * (KVIN / 4));
  cvt_pad<<<15360, 256, 0, stream>>>(W_vm, Wvmh, 15069, KVIN / 4, 1024 * (KVIN / 4));

  // ---- vin = Ap @ Wvm^T  (split-K x16, z-fastest for XCD/L2 locality) ----
  glds5<true, 0, false, 1, 0><<<dim3(16, 4, 8), 256, 0, stream>>>(
      Aph, Wvmh, nullptr, nullptr, part,
      1024, KVIN, KVIN, KVIN, 1024, 960, 0, 0, 524288);
  reduce_pe<<<512, 256, 0, stream>>>(part, one_hot, W_obj, b_vm, x, xh);

  // Wvr bf16 (reuse wvm region; Wvm dead after vin GEMM above)
  cvt_flat<<<15069, 256, 0, stream>>>(W_vr, Wvrh, 15069 * 256);

  // ---- hidden = audio @ W_af^T + b_af ----
  cvt_flat<<<384, 256, 0, stream>>>(audio, audh, 512 * 192);
  glds5<false, 0, false, 0, 0><<<dim3(8, 4, 6), 256, 0, stream>>>(
      audh, W_af, nullptr, nullptr, part,
      1024, 768, 768, 768, 1024, 128, 0, 0, 524288);
  combine<false><<<512, 256, 0, stream>>>(part, b_af, hidh, 6, 524288, 131072, 256);

  // ---- self attention ----
  glds5<false, 0, false, 0, 0><<<dim3(24, 4, 4), 256, 0, stream>>>(
      xh, Wqkv_sa, nullptr, nullptr, part,
      3072, 1024, 1024, 1024, 3072, 256, 0, 0, 1572864);
  combine<false><<<1536, 256, 0, stream>>>(part, bqkv_sa, qkvh, 4, 1572864, 393216, 768);
  vT_parts<<<dim3(16, 32), 256, 0, stream>>>(part, bqkv_sa, vth);
  // scores partials: z = head*2 + ks (kChunk=128 selects head cols automatically)
  glds5<true, 0, true, 0, 0><<<dim3(4, 4, 8), 256, 0, stream>>>(
      qkvh, qkvh + 1024, nullptr, nullptr, scores,
      512, 1024, 3072, 3072, 512, 128, 0, 0, 262144);
  softmax_alibi<<<dim3(512, 4), 256, 0, stream>>>(scores, atth);
  // ctx partials: z = head*4 + ks (ZDIV=4), fp32 partials -> combine_pv
  glds5<true, 0, false, 0, 4><<<dim3(2, 4, 16), 256, 0, stream>>>(
      atth, vth, nullptr, nullptr, pvpart,
      256, 512, 512, 512, 256, 128, 262144, 131072, 131072);
  combine_pv<<<512, 256, 0, stream>>>(pvpart, ctxh);
  // out proj + LN
  glds5<false, 0, false, 0, 0><<<dim3(8, 4, 8), 256, 0, stream>>>(
      ctxh, Wo_sa, nullptr, nullptr, part,
      1024, 1024, 1024, 1024, 1024, 128, 0, 0, 524288);
  ln_parts<<<512, 256, 0, stream>>>(part, 8, bo_sa, x, xh, g1, be1);

  // ---- cross attention: bool mask == identity -> V then O projection ----
  glds5<false, 0, false, 0, 0><<<dim3(8, 4, 8), 256, 0, stream>>>(
      hidh, Wqkv_ca + (size_t)2048 * 1024, nullptr, nullptr, part,
      1024, 1024, 1024, 1024, 1024, 128, 0, 0, 524288);
  combine<false><<<512, 256, 0, stream>>>(part, bqkv_ca + 2048, cvh, 8, 524288, 131072, 256);
  glds5<false, 0, false, 0, 0><<<dim3(8, 4, 8), 256, 0, stream>>>(
      cvh, Wo_ca, nullptr, nullptr, part,
      1024, 1024, 1024, 1024, 1024, 128, 0, 0, 524288);
  ln_parts<<<512, 256, 0, stream>>>(part, 8, bo_ca, x, xh, g2, be2);

  // ---- feed forward ----
  glds5<false, 0, false, 0, 0><<<dim3(16, 4, 4), 256, 0, stream>>>(
      xh, W1, nullptr, nullptr, part,
      2048, 1024, 1024, 1024, 2048, 256, 0, 0, 1048576);
  combine<true><<<1024, 256, 0, stream>>>(part, b1, h1h, 4, 1048576, 262144, 512);
  glds5<false, 0, false, 0, 0><<<dim3(8, 4, 8), 256, 0, stream>>>(
      h1h, W2, nullptr, nullptr, part,
      1024, 2048, 2048, 2048, 1024, 256, 0, 0, 524288);
  ln_parts<<<512, 256, 0, stream>>>(part, 8, b2, x, xh, g3, be3);

  // ---- final projection: out = x @ W_vr^T + b_vr + tmpl  (XCD n-swizzle) ----
  glds5<true, 2, false, 2, 0><<<dim3(480, 1, 1), 256, 0, stream>>>(
      xh, Wvrh, b_vr, tmpl, out,
      15069, 1024, 1024, 1024, 15069, 0, 0, 0, 0);
}